// Round 13
// baseline (2227.869 us; speedup 1.0000x reference)
//
#include <hip/hip_runtime.h>

#define NB 16
#define NS 12
#define NN 20000
#define NH 128
#define NP 3
#define NE 640000
#define NL 2
#define EPSV 1e-5f
#define BCK 8                 // batches per chunk
#define NMC (NN*BCK)          // 160000 rows per chunk (m = n*8 + bl)
#define NGEMM (NMC/256)       // 625 blocks for fused gemm
#define NREG (BCK*4)          // 32 (batch,quarter) regions per chunk
#define NGPB 1250             // NN/16 node-groups per region (16 dsts/block)

typedef __attribute__((ext_vector_type(8))) short short8;
typedef __attribute__((ext_vector_type(4))) float f32x4;
typedef __attribute__((ext_vector_type(4))) unsigned int u32x4;

__device__ __forceinline__ unsigned short f2bf(float f){
  unsigned int x = __float_as_uint(f);
  unsigned int r = x + 0x7FFFu + ((x >> 16) & 1u);
  return (unsigned short)(r >> 16);
}
__device__ __forceinline__ unsigned int pack2(float a, float b){
  return (unsigned int)f2bf(a) | ((unsigned int)f2bf(b) << 16);
}
__device__ __forceinline__ float bflo(unsigned int u){ return __uint_as_float(u << 16); }
__device__ __forceinline__ float bfhi(unsigned int u){ return __uint_as_float(u & 0xFFFF0000u); }

// ---------------- edge dtype detect ----------------
__global__ void k_detect(const int* __restrict__ ei, int* __restrict__ flag){
  __shared__ int any;
  if(threadIdx.x==0) any=0;
  __syncthreads();
  int nz=0;
  for(int i=threadIdx.x;i<4096;i+=256) if(ei[2*i+1]!=0) nz=1;
  if(nz) atomicOr(&any,1);
  __syncthreads();
  if(threadIdx.x==0) *flag = any ? 0 : 1;   // 1 = int64 layout
}

// ---------------- graph preprocessing ----------------
__global__ void k_count(const int* __restrict__ ei, const int* __restrict__ flag,
                        int* __restrict__ deg_src, int* __restrict__ cnt_dst){
  int e = blockIdx.x*256+threadIdx.x;
  if(e<NE){
    int f = *flag;
    int s = f ? ei[2*e]        : ei[e];
    int d = f ? ei[2*NE + 2*e] : ei[NE+e];
    atomicAdd(&deg_src[s],1);
    atomicAdd(&cnt_dst[d],1);
  }
}

__global__ void k_dis(const int* __restrict__ deg, float* __restrict__ dis){
  int n = blockIdx.x*256+threadIdx.x;
  if(n<NN) dis[n] = deg[n]>0 ? rsqrtf((float)deg[n]) : 0.f;
}

__global__ __launch_bounds__(1024) void k_scan(const int* __restrict__ cnt, int* __restrict__ offs){
  __shared__ int warpsum[16];
  __shared__ int carry;
  if(threadIdx.x==0) carry=0;
  __syncthreads();
  int lane = threadIdx.x & 63, wid = threadIdx.x >> 6;
  for(int base=0;base<NN;base+=1024){
    int i = base+threadIdx.x;
    int v = (i<NN)?cnt[i]:0;
    int x = v;
    #pragma unroll
    for(int off=1;off<64;off<<=1){
      int y=__shfl_up(x,off,64);
      if(lane>=off) x+=y;
    }
    if(lane==63) warpsum[wid]=x;
    __syncthreads();
    if(wid==0){
      int w=(lane<16)?warpsum[lane]:0;
      #pragma unroll
      for(int off=1;off<16;off<<=1){
        int y=__shfl_up(w,off,64);
        if(lane>=off) w+=y;
      }
      if(lane<16) warpsum[lane]=w;
    }
    __syncthreads();
    int incl = x + ((wid>0)?warpsum[wid-1]:0) + carry;
    if(i<NN) offs[i]=incl-v;
    __syncthreads();
    if(threadIdx.x==1023) carry=incl;
    __syncthreads();
  }
  if(threadIdx.x==0) offs[NN]=carry;
}

__global__ void k_scatter(const int* __restrict__ ei, const int* __restrict__ flag,
                          const int* __restrict__ offs, int* __restrict__ fill,
                          const float* __restrict__ dis, int2* __restrict__ edata){
  int e = blockIdx.x*256+threadIdx.x;
  if(e<NE){
    int f = *flag;
    int s = f ? ei[2*e]        : ei[e];
    int d = f ? ei[2*NE + 2*e] : ei[NE+e];
    int pos = offs[d] + atomicAdd(&fill[d],1);
    edata[pos] = make_int2(s, (int)f2bf(-dis[s]*dis[d]));   // bf16 weight in low 16
  }
}

// ---------------- per-dst src-sort (deterministic rank sort; canonical order) ----------------
__global__ __launch_bounds__(64) void k_sortseg(const int* __restrict__ offs, int2* __restrict__ edata){
  __shared__ int2 seg[128];
  int v = blockIdx.x;
  int e0 = offs[v], e1 = offs[v+1], d = e1 - e0;
  int lane = threadIdx.x;
  if(d < 2 || d > 128) return;          // unsorted is still correct
  for(int i=lane; i<d; i+=64) seg[i] = edata[e0+i];
  __syncthreads();
  for(int i=lane; i<d; i+=64){
    int2 me = seg[i];
    int r = 0;
    for(int j=0; j<d; j++){
      int2 ot = seg[j];
      r += (ot.x < me.x) || (ot.x == me.x && j < i);
    }
    edata[e0 + r] = me;
  }
}

// ---------------- folded weights: U^T[(l*9+tm*3+kw)][f][k] = sum_i cheb_w[l][tm][k][i]*conv_w[l][f][i][kw]
// grid 72: blk = (l*9+tm*3+kw)*4 + kq ; computes k-quarter kq (32 k values)
__global__ __launch_bounds__(256) void k_prepu(const float* __restrict__ cw, const float* __restrict__ vw,
                                               unsigned short* __restrict__ Ubt){
  __shared__ float A[32][129];
  int blk = blockIdx.x;
  int kq = blk & 3; int combo = blk >> 2;      // combo = l*9+tm*3+kw
  int kw = combo % 3, tm = (combo/3) % 3, l = combo / 9;
  int t = threadIdx.x;
  const float* Ap = cw + (size_t)(l*3+tm)*NH*NH + kq*32*NH;   // rows k, cols i
  for(int i=t;i<32*NH;i+=256) A[i>>7][i&127] = Ap[i];
  __syncthreads();
  int f = t >> 1, kh = (t & 1) * 16;
  float acc[16];
  #pragma unroll
  for(int k=0;k<16;k++) acc[k]=0.f;
  const float* Bp = vw + ((size_t)(l*NH + f)*NH)*3 + kw;      // conv_w[l][f][i][kw]
  for(int i=0;i<NH;i++){
    float bv = Bp[i*3];
    #pragma unroll
    for(int k=0;k<16;k++) acc[k] = fmaf(A[kh+k][i], bv, acc[k]);
  }
  unsigned short* Up = Ubt + ((size_t)combo*NH + f)*NH + kq*32 + kh;
  #pragma unroll
  for(int k=0;k<16;k++) Up[k] = f2bf(acc[k]);
}

// folded bias through cheb bias: bp[l][kw][f] = sum_i cheb_b[l][i] * conv_w[l][f][i][kw]
__global__ __launch_bounds__(128) void k_prepb(const float* __restrict__ cb, const float* __restrict__ vw,
                                               float* __restrict__ bp){
  int blk = blockIdx.x; int kw = blk % 3, l = blk / 3;
  int f = threadIdx.x;
  const float* Bp = vw + ((size_t)(l*NH + f)*NH)*3 + kw;
  const float* c0 = cb + l*NH;
  float s = 0.f;
  for(int i=0;i<NH;i++) s = fmaf(c0[i], Bp[i*3], s);
  bp[(size_t)blk*NH + f] = s;
}

// ---------------- input projection -> h (f32, m-layout) + hbq (bf16, region layout) ----------------
__global__ __launch_bounds__(256) void k_inproj(const float* __restrict__ x, const float* __restrict__ w,
                                                const float* __restrict__ bb, float* __restrict__ h,
                                                unsigned int* __restrict__ hbq, int b0){
  __shared__ float ws_[NS*NH];
  int t=threadIdx.x;
  for(int i=t;i<NS*NH;i+=256) ws_[i]=w[i];
  __syncthreads();
  int lane = t & 63;
  int m = blockIdx.x*4 + (t>>6);       // < NMC
  int n = m >> 3, bl = m & 7;
  const float* xp = x + (size_t)(b0+bl)*NS*NN + n;
  float a0 = bb[2*lane], a1 = bb[2*lane+1];
  #pragma unroll
  for(int s=0;s<NS;s++){
    float xv = xp[(size_t)s*NN];
    a0 = fmaf(xv, ws_[s*NH+2*lane],   a0);
    a1 = fmaf(xv, ws_[s*NH+2*lane+1], a1);
  }
  ((float2*)h)[(size_t)m*64 + lane] = make_float2(a0,a1);
  hbq[((size_t)(bl*4 + (lane>>4))*NN + n)*16 + (lane&15)] = pack2(a0,a1);
}

// ---------------- propagation: region-major grid, 16 dsts/block, dot2 edge-pairing ----------------
#define DOT2(ACC,AB,WP) asm("v_dot2_f32_bf16 %0, %1, %2, %0" : "+v"(ACC) : "v"(AB), "v"(WP))

template<bool COMBINE>
__global__ __launch_bounds__(256) void k_prop(const uint4* __restrict__ in, const uint4* __restrict__ sub,
                                              uint4* __restrict__ outp, const int* __restrict__ offs,
                                              const int2* __restrict__ edata){
  int b = blockIdx.x;
  int region = b / NGPB;               // sequential in dispatch order
  int ng = b % NGPB;
  int t = threadIdx.x;
  int dst = ng*16 + (t>>4);
  int ep = (t>>2)&3, sl = t&3;
  const uint4* base = in + (size_t)region*NN*4;
  int e0 = offs[dst] + ep, e1 = offs[dst+1];
  float a0=0.f,a1=0.f,a2=0.f,a3=0.f,a4=0.f,a5=0.f,a6=0.f,a7=0.f;
  int e = e0;
  for(; e+4 < e1; e += 8){
    int2 m0 = edata[e], m1 = edata[e+4];
    uint4 p0 = base[(size_t)m0.x*4 + sl];
    uint4 p1 = base[(size_t)m1.x*4 + sl];
    unsigned int wp = ((unsigned int)m0.y & 0xFFFFu) | ((unsigned int)m1.y << 16);
    unsigned int lo, hi;
    lo = __builtin_amdgcn_perm(p1.x, p0.x, 0x05040100u);
    hi = __builtin_amdgcn_perm(p1.x, p0.x, 0x07060302u);
    DOT2(a0, lo, wp); DOT2(a1, hi, wp);
    lo = __builtin_amdgcn_perm(p1.y, p0.y, 0x05040100u);
    hi = __builtin_amdgcn_perm(p1.y, p0.y, 0x07060302u);
    DOT2(a2, lo, wp); DOT2(a3, hi, wp);
    lo = __builtin_amdgcn_perm(p1.z, p0.z, 0x05040100u);
    hi = __builtin_amdgcn_perm(p1.z, p0.z, 0x07060302u);
    DOT2(a4, lo, wp); DOT2(a5, hi, wp);
    lo = __builtin_amdgcn_perm(p1.w, p0.w, 0x05040100u);
    hi = __builtin_amdgcn_perm(p1.w, p0.w, 0x07060302u);
    DOT2(a6, lo, wp); DOT2(a7, hi, wp);
  }
  if(e < e1){
    int2 m = edata[e];
    uint4 p = base[(size_t)m.x*4 + sl];
    float w = __uint_as_float(((unsigned int)m.y) << 16);
    a0=fmaf(w,bflo(p.x),a0); a1=fmaf(w,bfhi(p.x),a1);
    a2=fmaf(w,bflo(p.y),a2); a3=fmaf(w,bfhi(p.y),a3);
    a4=fmaf(w,bflo(p.z),a4); a5=fmaf(w,bfhi(p.z),a5);
    a6=fmaf(w,bflo(p.w),a6); a7=fmaf(w,bfhi(p.w),a7);
  }
  a0+=__shfl_xor(a0,4,64); a1+=__shfl_xor(a1,4,64); a2+=__shfl_xor(a2,4,64); a3+=__shfl_xor(a3,4,64);
  a4+=__shfl_xor(a4,4,64); a5+=__shfl_xor(a5,4,64); a6+=__shfl_xor(a6,4,64); a7+=__shfl_xor(a7,4,64);
  a0+=__shfl_xor(a0,8,64); a1+=__shfl_xor(a1,8,64); a2+=__shfl_xor(a2,8,64); a3+=__shfl_xor(a3,8,64);
  a4+=__shfl_xor(a4,8,64); a5+=__shfl_xor(a5,8,64); a6+=__shfl_xor(a6,8,64); a7+=__shfl_xor(a7,8,64);
  if(ep==0){
    size_t o = (size_t)region*NN*4 + (size_t)dst*4 + sl;
    if(COMBINE){
      uint4 hv = sub[o];
      a0 = 2.f*a0 - bflo(hv.x); a1 = 2.f*a1 - bfhi(hv.x);
      a2 = 2.f*a2 - bflo(hv.y); a3 = 2.f*a3 - bfhi(hv.y);
      a4 = 2.f*a4 - bflo(hv.z); a5 = 2.f*a5 - bfhi(hv.z);
      a6 = 2.f*a6 - bflo(hv.w); a7 = 2.f*a7 - bfhi(hv.w);
    }
    uint4 r;
    r.x = pack2(a0,a1); r.y = pack2(a2,a3); r.z = pack2(a4,a5); r.w = pack2(a6,a7);
    outp[o] = r;
  }
}

// ---------------- FUSED cheb+conv (MFMA, 64 rows/wave) + bias + residual(f32) + LN + relu ----------------
// out[row,f] = sum_tm sum_kw T_tm[row+(kw-1)*8] @ U[tm][kw]  (+ folded bias, boundary-corrected)
// LAST=false: write H (f32) + Hbo (region layout).  LAST=true: fused output projection.
template<bool LAST>
__global__ __launch_bounds__(256) void k_cc(const unsigned short* __restrict__ T0,
                                            const unsigned short* __restrict__ T1,
                                            const unsigned short* __restrict__ T2,
                                            const unsigned short* __restrict__ Ubl,
                                            const float* __restrict__ bp,   // [3][128]
                                            const float* __restrict__ cvb,  // conv_b layer
                                            const float* __restrict__ lg, const float* __restrict__ lb,
                                            float* __restrict__ H, unsigned short* __restrict__ Hbo,
                                            const float* __restrict__ ow, const float* __restrict__ ob,
                                            float* __restrict__ out, int b0){
  int t = threadIdx.x;
  int lane = t & 63, w = t >> 6;
  int c = lane & 15, g = lane >> 4;
  int rbase = blockIdx.x*256 + w*64;
  const unsigned short* Ts[3] = {T0, T1, T2};
  f32x4 acc[4][8];
  #pragma unroll
  for(int i=0;i<4;i++)
    #pragma unroll
    for(int j=0;j<8;j++) acc[i][j] = (f32x4){0.f,0.f,0.f,0.f};
  short8 zf = {0,0,0,0,0,0,0,0};
  for(int kc=0; kc<4; kc++){
    #pragma unroll
    for(int tm=0; tm<3; tm++){
      const unsigned short* Tp = Ts[tm];
      short8 af[9];                       // rows rbase + 8*(q-1) + c ; frag(rt,kw) = af[2rt+kw]
      #pragma unroll
      for(int q=0;q<9;q++){
        int rowA = rbase + 8*(q-1) + c;
        if((unsigned)rowA < (unsigned)NMC){
          int n = rowA >> 3, bl = rowA & 7;
          af[q] = *(const short8*)(Tp + ((size_t)(bl*4+kc)*NN + n)*32 + 8*g);
        } else af[q] = zf;
      }
      #pragma unroll
      for(int kw=0; kw<3; kw++){
        #pragma unroll
        for(int ft=0; ft<8; ft++){
          short8 bf_ = *(const short8*)(Ubl + (((size_t)(tm*3+kw)*NH + 16*ft + c)<<7) + kc*32 + 8*g);
          #pragma unroll
          for(int rt=0; rt<4; rt++)
            acc[rt][ft] = __builtin_amdgcn_mfma_f32_16x16x32_bf16(af[2*rt+kw], bf_, acc[rt][ft], 0, 0, 0);
        }
      }
    }
  }
  float gv[8], bv[8], bint[8], c0a[8], c2a[8];
  #pragma unroll
  for(int ft=0; ft<8; ft++){
    int f = 16*ft + c;
    gv[ft] = lg[f]; bv[ft] = lb[f];
    float b0v = bp[f], b1v = bp[NH+f], b2v = bp[2*NH+f];
    bint[ft] = cvb[f] + b0v + b1v + b2v;
    c0a[ft] = b0v; c2a[ft] = b2v;
  }
  #pragma unroll
  for(int rt=0; rt<4; rt++){
    #pragma unroll
    for(int r=0;r<4;r++){
      int row = rbase + rt*16 + 4*g + r;
      size_t rbs = (size_t)row*NH;
      int n = row >> 3, bl = row & 7;
      bool bnd0 = (n == 0), bnd2 = (n == NN-1);
      float vals[8];
      float s = 0.f;
      #pragma unroll
      for(int ft=0; ft<8; ft++){
        float res = H[rbs + 16*ft + c];
        float bb = bint[ft];
        if(bnd0) bb -= c0a[ft];
        if(bnd2) bb -= c2a[ft];
        float v = acc[rt][ft][r] + bb + res;
        vals[ft] = v;
        s += v;
      }
      s += __shfl_xor(s,1,64); s += __shfl_xor(s,2,64);
      s += __shfl_xor(s,4,64); s += __shfl_xor(s,8,64);
      float mu = s * (1.f/128.f);
      float q = 0.f;
      #pragma unroll
      for(int ft=0; ft<8; ft++){ float d = vals[ft]-mu; q += d*d; }
      q += __shfl_xor(q,1,64); q += __shfl_xor(q,2,64);
      q += __shfl_xor(q,4,64); q += __shfl_xor(q,8,64);
      float rs = rsqrtf(q*(1.f/128.f) + EPSV);
      if(!LAST){
        #pragma unroll
        for(int ft=0; ft<8; ft++){
          float y = (vals[ft]-mu)*rs*gv[ft] + bv[ft];
          y = fmaxf(y, 0.f);
          H[rbs + 16*ft + c] = y;
          int f = 16*ft + c;
          Hbo[((size_t)(bl*4+(f>>5))*NN + n)*32 + (f&31)] = f2bf(y);
        }
      } else {
        float p0=0.f, p1=0.f, p2=0.f;
        #pragma unroll
        for(int ft=0; ft<8; ft++){
          float y = (vals[ft]-mu)*rs*gv[ft] + bv[ft];
          y = fmaxf(y, 0.f);
          int f = 16*ft + c;
          p0 = fmaf(y, ow[f*3+0], p0);
          p1 = fmaf(y, ow[f*3+1], p1);
          p2 = fmaf(y, ow[f*3+2], p2);
        }
        p0 += __shfl_xor(p0,1,64); p0 += __shfl_xor(p0,2,64);
        p0 += __shfl_xor(p0,4,64); p0 += __shfl_xor(p0,8,64);
        p1 += __shfl_xor(p1,1,64); p1 += __shfl_xor(p1,2,64);
        p1 += __shfl_xor(p1,4,64); p1 += __shfl_xor(p1,8,64);
        p2 += __shfl_xor(p2,1,64); p2 += __shfl_xor(p2,2,64);
        p2 += __shfl_xor(p2,4,64); p2 += __shfl_xor(p2,8,64);
        if(c==0){
          int nn = row >> 3, bl2 = b0 + (row & 7);
          out[((size_t)bl2*NP+0)*NN+nn] = p0 + ob[0];
          out[((size_t)bl2*NP+1)*NN+nn] = p1 + ob[1];
          out[((size_t)bl2*NP+2)*NN+nn] = p2 + ob[2];
        }
      }
    }
  }
}

extern "C" void kernel_launch(void* const* d_in, const int* in_sizes, int n_in,
                              void* d_out, int out_size, void* d_ws, size_t ws_size,
                              hipStream_t stream) {
  const float* x      = (const float*)d_in[0];
  const int*   ei     = (const int*)d_in[1];
  const float* in_w   = (const float*)d_in[2];
  const float* in_b   = (const float*)d_in[3];
  const float* cheb_w = (const float*)d_in[4];
  const float* cheb_b = (const float*)d_in[5];
  const float* conv_w = (const float*)d_in[6];
  const float* conv_b = (const float*)d_in[7];
  const float* ln_g   = (const float*)d_in[8];
  const float* ln_b   = (const float*)d_in[9];
  const float* out_w  = (const float*)d_in[10];
  const float* out_b  = (const float*)d_in[11];
  float* out = (float*)d_out;

  char* ws = (char*)d_ws;
  size_t off = 0;
  auto alloc = [&](size_t bytes)->void*{
    void* p = ws + off;
    off += (bytes + 255) & ~(size_t)255;
    return p;
  };
  // ---- fixed region (~6.5 MB) ----
  int* flag    = (int*)alloc(4);
  int* deg     = (int*)alloc(NN*4);
  int* cnt     = (int*)alloc(NN*4);
  int* fill    = (int*)alloc(NN*4);
  int* offs    = (int*)alloc((NN+1)*4);
  float* dis   = (float*)alloc(NN*4);
  int2* edata  = (int2*)alloc((size_t)NE*8);
  unsigned short* Ubt = (unsigned short*)alloc((size_t)NL*9*NH*NH*2);
  float* bp    = (float*)alloc((size_t)NL*3*NH*4);
  // ---- chunk activation buffers: 82 + 4*41 MB = 246 MB ----
  const size_t fullb = ((size_t)NMC*NH*4 + 255) & ~(size_t)255;
  const size_t halfb = ((size_t)NMC*NH*2 + 255) & ~(size_t)255;
  float*          h   = (float*)alloc(fullb);
  unsigned short* hbA = (unsigned short*)alloc(halfb);
  unsigned short* hbB = (unsigned short*)alloc(halfb);
  unsigned short* t1b = (unsigned short*)alloc(halfb);
  unsigned short* t2b = (unsigned short*)alloc(halfb);

  hipMemsetAsync(deg, 0, NN*4, stream);
  hipMemsetAsync(cnt, 0, NN*4, stream);
  hipMemsetAsync(fill, 0, NN*4, stream);

  k_detect<<<1,256,0,stream>>>(ei,flag);
  k_count<<<(NE+255)/256,256,0,stream>>>(ei,flag,deg,cnt);
  k_dis<<<(NN+255)/256,256,0,stream>>>(deg,dis);
  k_scan<<<1,1024,0,stream>>>(cnt,offs);
  k_scatter<<<(NE+255)/256,256,0,stream>>>(ei,flag,offs,fill,dis,edata);
  k_sortseg<<<NN,64,0,stream>>>(offs,edata);
  k_prepu<<<NL*9*4,256,0,stream>>>(cheb_w,conv_w,Ubt);
  k_prepb<<<NL*3,128,0,stream>>>(cheb_b,conv_w,bp);

  for(int b0=0; b0<NB; b0+=BCK){
    k_inproj<<<NMC/4,256,0,stream>>>(x,in_w,in_b,h,(unsigned int*)hbA,b0);
    unsigned short* cur = hbA;
    unsigned short* nxt = hbB;
    for(int l=0;l<NL;l++){
      k_prop<false><<<NREG*NGPB,256,0,stream>>>((const uint4*)cur,  nullptr,
                                                (uint4*)t1b, offs, edata);
      k_prop<true ><<<NREG*NGPB,256,0,stream>>>((const uint4*)t1b, (const uint4*)cur,
                                                (uint4*)t2b, offs, edata);
      if(l==0)
        k_cc<false><<<NGEMM,256,0,stream>>>(cur, t1b, t2b,
                                            Ubt + (size_t)l*9*NH*NH, bp + (size_t)l*3*NH,
                                            conv_b + l*NH, ln_g + l*NH, ln_b + l*NH,
                                            h, nxt, out_w, out_b, out, b0);
      else
        k_cc<true ><<<NGEMM,256,0,stream>>>(cur, t1b, t2b,
                                            Ubt + (size_t)l*9*NH*NH, bp + (size_t)l*3*NH,
                                            conv_b + l*NH, ln_g + l*NH, ln_b + l*NH,
                                            h, nxt, out_w, out_b, out, b0);
      unsigned short* tmp = cur; cur = nxt; nxt = tmp;
    }
  }
}

// Round 14
// 2099.714 us; speedup vs baseline: 1.0610x; 1.0610x over previous
//
#include <hip/hip_runtime.h>

#define NB 16
#define NS 12
#define NN 20000
#define NH 128
#define NP 3
#define NE 640000
#define NL 2
#define EPSV 1e-5f
#define BCK 8                 // batches per chunk
#define NMC (NN*BCK)          // 160000 rows per chunk (m = n*8 + bl)
#define NGEMM (NMC/128)       // 1250 blocks for cheb/conv (128 rows per block, 32/wave)
#define NREG (BCK*4)          // 32 (batch,quarter) regions per chunk
#define NGPB 1250             // NN/16 node-groups per region (16 dsts/block)

typedef __attribute__((ext_vector_type(8))) short short8;
typedef __attribute__((ext_vector_type(4))) float f32x4;
typedef __attribute__((ext_vector_type(4))) unsigned int u32x4;

__device__ __forceinline__ unsigned short f2bf(float f){
  unsigned int x = __float_as_uint(f);
  unsigned int r = x + 0x7FFFu + ((x >> 16) & 1u);
  return (unsigned short)(r >> 16);
}
__device__ __forceinline__ unsigned int pack2(float a, float b){
  return (unsigned int)f2bf(a) | ((unsigned int)f2bf(b) << 16);
}
__device__ __forceinline__ float bflo(unsigned int u){ return __uint_as_float(u << 16); }
__device__ __forceinline__ float bfhi(unsigned int u){ return __uint_as_float(u & 0xFFFF0000u); }

// ---------------- edge dtype detect ----------------
__global__ void k_detect(const int* __restrict__ ei, int* __restrict__ flag){
  __shared__ int any;
  if(threadIdx.x==0) any=0;
  __syncthreads();
  int nz=0;
  for(int i=threadIdx.x;i<4096;i+=256) if(ei[2*i+1]!=0) nz=1;
  if(nz) atomicOr(&any,1);
  __syncthreads();
  if(threadIdx.x==0) *flag = any ? 0 : 1;   // 1 = int64 layout
}

// ---------------- graph preprocessing ----------------
__global__ void k_count(const int* __restrict__ ei, const int* __restrict__ flag,
                        int* __restrict__ deg_src, int* __restrict__ cnt_dst){
  int e = blockIdx.x*256+threadIdx.x;
  if(e<NE){
    int f = *flag;
    int s = f ? ei[2*e]        : ei[e];
    int d = f ? ei[2*NE + 2*e] : ei[NE+e];
    atomicAdd(&deg_src[s],1);
    atomicAdd(&cnt_dst[d],1);
  }
}

__global__ void k_dis(const int* __restrict__ deg, float* __restrict__ dis){
  int n = blockIdx.x*256+threadIdx.x;
  if(n<NN) dis[n] = deg[n]>0 ? rsqrtf((float)deg[n]) : 0.f;
}

__global__ __launch_bounds__(1024) void k_scan(const int* __restrict__ cnt, int* __restrict__ offs){
  __shared__ int warpsum[16];
  __shared__ int carry;
  if(threadIdx.x==0) carry=0;
  __syncthreads();
  int lane = threadIdx.x & 63, wid = threadIdx.x >> 6;
  for(int base=0;base<NN;base+=1024){
    int i = base+threadIdx.x;
    int v = (i<NN)?cnt[i]:0;
    int x = v;
    #pragma unroll
    for(int off=1;off<64;off<<=1){
      int y=__shfl_up(x,off,64);
      if(lane>=off) x+=y;
    }
    if(lane==63) warpsum[wid]=x;
    __syncthreads();
    if(wid==0){
      int w=(lane<16)?warpsum[lane]:0;
      #pragma unroll
      for(int off=1;off<16;off<<=1){
        int y=__shfl_up(w,off,64);
        if(lane>=off) w+=y;
      }
      if(lane<16) warpsum[lane]=w;
    }
    __syncthreads();
    int incl = x + ((wid>0)?warpsum[wid-1]:0) + carry;
    if(i<NN) offs[i]=incl-v;
    __syncthreads();
    if(threadIdx.x==1023) carry=incl;
    __syncthreads();
  }
  if(threadIdx.x==0) offs[NN]=carry;
}

__global__ void k_scatter(const int* __restrict__ ei, const int* __restrict__ flag,
                          const int* __restrict__ offs, int* __restrict__ fill,
                          const float* __restrict__ dis, int2* __restrict__ edata){
  int e = blockIdx.x*256+threadIdx.x;
  if(e<NE){
    int f = *flag;
    int s = f ? ei[2*e]        : ei[e];
    int d = f ? ei[2*NE + 2*e] : ei[NE+e];
    int pos = offs[d] + atomicAdd(&fill[d],1);
    edata[pos] = make_int2(s, (int)f2bf(-dis[s]*dis[d]));   // bf16 weight in low 16
  }
}

// ---------------- per-dst src-sort (deterministic rank sort; canonical order) ----------------
__global__ __launch_bounds__(64) void k_sortseg(const int* __restrict__ offs, int2* __restrict__ edata){
  __shared__ int2 seg[128];
  int v = blockIdx.x;
  int e0 = offs[v], e1 = offs[v+1], d = e1 - e0;
  int lane = threadIdx.x;
  if(d < 2 || d > 128) return;          // unsorted is still correct
  for(int i=lane; i<d; i+=64) seg[i] = edata[e0+i];
  __syncthreads();
  for(int i=lane; i<d; i+=64){
    int2 me = seg[i];
    int r = 0;
    for(int j=0; j<d; j++){
      int2 ot = seg[j];
      r += (ot.x < me.x) || (ot.x == me.x && j < i);
    }
    edata[e0 + r] = me;
  }
}

// weights -> bf16 B^T: Wct[l][tm][f][k] = cheb_w[l][tm][k][f];  Wvt[l][kw][f][i] = conv_w[l][f][i][kw]
__global__ void k_prepw(const float* __restrict__ cw, const float* __restrict__ vw,
                        unsigned short* __restrict__ Wct, unsigned short* __restrict__ Wvt){
  int idx = blockIdx.x*256+threadIdx.x;
  if(idx < NL*3*NH*NH){
    int k = idx & 127;
    int r = idx >> 7;
    int f = r & 127; r >>= 7;
    int sel = r % 3; int l = r / 3;
    Wct[idx] = f2bf(cw[(((l*3+sel)*NH + k)*NH) + f]);
    Wvt[idx] = f2bf(vw[((l*NH + f)*NH + k)*3 + sel]);
  }
}

// ---------------- input projection -> h (f32, m-layout) + hbq (bf16, region layout) ----------------
// region layout: [bl][q][n][32feats];  u32 row = 16 words
__global__ __launch_bounds__(256) void k_inproj(const float* __restrict__ x, const float* __restrict__ w,
                                                const float* __restrict__ bb, float* __restrict__ h,
                                                unsigned int* __restrict__ hbq, int b0){
  __shared__ float ws_[NS*NH];
  int t=threadIdx.x;
  for(int i=t;i<NS*NH;i+=256) ws_[i]=w[i];
  __syncthreads();
  int lane = t & 63;
  int m = blockIdx.x*4 + (t>>6);       // < NMC
  int n = m >> 3, bl = m & 7;
  const float* xp = x + (size_t)(b0+bl)*NS*NN + n;
  float a0 = bb[2*lane], a1 = bb[2*lane+1];
  #pragma unroll
  for(int s=0;s<NS;s++){
    float xv = xp[(size_t)s*NN];
    a0 = fmaf(xv, ws_[s*NH+2*lane],   a0);
    a1 = fmaf(xv, ws_[s*NH+2*lane+1], a1);
  }
  ((float2*)h)[(size_t)m*64 + lane] = make_float2(a0,a1);
  hbq[((size_t)(bl*4 + (lane>>4))*NN + n)*16 + (lane&15)] = pack2(a0,a1);
}

// ---------------- propagation: region-major grid, 16 dsts/block, dot2 edge-pairing ----------------
#define DOT2(ACC,AB,WP) asm("v_dot2_f32_bf16 %0, %1, %2, %0" : "+v"(ACC) : "v"(AB), "v"(WP))

template<bool COMBINE>
__global__ __launch_bounds__(256) void k_prop(const uint4* __restrict__ in, const uint4* __restrict__ sub,
                                              uint4* __restrict__ outp, const int* __restrict__ offs,
                                              const int2* __restrict__ edata){
  int b = blockIdx.x;
  int region = b / NGPB;               // sequential in dispatch order
  int ng = b % NGPB;
  int t = threadIdx.x;
  int dst = ng*16 + (t>>4);
  int ep = (t>>2)&3, sl = t&3;
  const uint4* base = in + (size_t)region*NN*4;
  int e0 = offs[dst] + ep, e1 = offs[dst+1];
  float a0=0.f,a1=0.f,a2=0.f,a3=0.f,a4=0.f,a5=0.f,a6=0.f,a7=0.f;
  int e = e0;
  for(; e+4 < e1; e += 8){
    int2 m0 = edata[e], m1 = edata[e+4];
    uint4 p0 = base[(size_t)m0.x*4 + sl];
    uint4 p1 = base[(size_t)m1.x*4 + sl];
    unsigned int wp = ((unsigned int)m0.y & 0xFFFFu) | ((unsigned int)m1.y << 16);
    unsigned int lo, hi;
    lo = __builtin_amdgcn_perm(p1.x, p0.x, 0x05040100u);
    hi = __builtin_amdgcn_perm(p1.x, p0.x, 0x07060302u);
    DOT2(a0, lo, wp); DOT2(a1, hi, wp);
    lo = __builtin_amdgcn_perm(p1.y, p0.y, 0x05040100u);
    hi = __builtin_amdgcn_perm(p1.y, p0.y, 0x07060302u);
    DOT2(a2, lo, wp); DOT2(a3, hi, wp);
    lo = __builtin_amdgcn_perm(p1.z, p0.z, 0x05040100u);
    hi = __builtin_amdgcn_perm(p1.z, p0.z, 0x07060302u);
    DOT2(a4, lo, wp); DOT2(a5, hi, wp);
    lo = __builtin_amdgcn_perm(p1.w, p0.w, 0x05040100u);
    hi = __builtin_amdgcn_perm(p1.w, p0.w, 0x07060302u);
    DOT2(a6, lo, wp); DOT2(a7, hi, wp);
  }
  if(e < e1){
    int2 m = edata[e];
    uint4 p = base[(size_t)m.x*4 + sl];
    float w = __uint_as_float(((unsigned int)m.y) << 16);
    a0=fmaf(w,bflo(p.x),a0); a1=fmaf(w,bfhi(p.x),a1);
    a2=fmaf(w,bflo(p.y),a2); a3=fmaf(w,bfhi(p.y),a3);
    a4=fmaf(w,bflo(p.z),a4); a5=fmaf(w,bfhi(p.z),a5);
    a6=fmaf(w,bflo(p.w),a6); a7=fmaf(w,bfhi(p.w),a7);
  }
  a0+=__shfl_xor(a0,4,64); a1+=__shfl_xor(a1,4,64); a2+=__shfl_xor(a2,4,64); a3+=__shfl_xor(a3,4,64);
  a4+=__shfl_xor(a4,4,64); a5+=__shfl_xor(a5,4,64); a6+=__shfl_xor(a6,4,64); a7+=__shfl_xor(a7,4,64);
  a0+=__shfl_xor(a0,8,64); a1+=__shfl_xor(a1,8,64); a2+=__shfl_xor(a2,8,64); a3+=__shfl_xor(a3,8,64);
  a4+=__shfl_xor(a4,8,64); a5+=__shfl_xor(a5,8,64); a6+=__shfl_xor(a6,8,64); a7+=__shfl_xor(a7,8,64);
  if(ep==0){
    size_t o = (size_t)region*NN*4 + (size_t)dst*4 + sl;
    if(COMBINE){
      uint4 hv = sub[o];
      a0 = 2.f*a0 - bflo(hv.x); a1 = 2.f*a1 - bfhi(hv.x);
      a2 = 2.f*a2 - bflo(hv.y); a3 = 2.f*a3 - bfhi(hv.y);
      a4 = 2.f*a4 - bflo(hv.z); a5 = 2.f*a5 - bfhi(hv.z);
      a6 = 2.f*a6 - bflo(hv.w); a7 = 2.f*a7 - bfhi(hv.w);
    }
    uint4 r;
    r.x = pack2(a0,a1); r.y = pack2(a2,a3); r.z = pack2(a4,a5); r.w = pack2(a6,a7);
    outp[o] = r;
  }
}

// ---------------- cheb matmul (MFMA, 32 rows/wave), region-layout activations ----------------
__global__ __launch_bounds__(256) void k_cheb(const unsigned short* __restrict__ T0,
                                              const unsigned short* __restrict__ T1,
                                              const unsigned short* __restrict__ T2,
                                              const unsigned short* __restrict__ Wct,
                                              const float* __restrict__ cb,
                                              unsigned short* __restrict__ outb){
  int t = threadIdx.x;
  int lane = t & 63, w = t >> 6;
  int c = lane & 15, g = lane >> 4;
  int rbase = blockIdx.x*128 + w*32;
  const unsigned short* Ts[3] = {T0, T1, T2};
  f32x4 acc[2][8];
  #pragma unroll
  for(int i=0;i<2;i++)
    #pragma unroll
    for(int j=0;j<8;j++) acc[i][j] = (f32x4){0.f,0.f,0.f,0.f};
  for(int kc=0; kc<4; kc++){
    #pragma unroll
    for(int tm=0; tm<3; tm++){
      short8 af[2];
      #pragma unroll
      for(int rt=0; rt<2; rt++){
        int m = rbase + rt*16 + c;
        int n = m >> 3, bl = m & 7;
        af[rt] = *(const short8*)(Ts[tm] + ((size_t)(bl*4+kc)*NN + n)*32 + 8*g);
      }
      #pragma unroll
      for(int ft=0; ft<8; ft++){
        short8 bf_ = *(const short8*)(Wct + (((size_t)tm*NH + 16*ft + c)<<7) + kc*32 + 8*g);
        #pragma unroll
        for(int rt=0; rt<2; rt++)
          acc[rt][ft] = __builtin_amdgcn_mfma_f32_16x16x32_bf16(af[rt], bf_, acc[rt][ft], 0, 0, 0);
      }
    }
  }
  float bias[8];
  #pragma unroll
  for(int ft=0; ft<8; ft++) bias[ft] = cb[16*ft + c];
  #pragma unroll
  for(int rt=0; rt<2; rt++){
    #pragma unroll
    for(int r=0;r<4;r++){
      int row = rbase + rt*16 + 4*g + r;
      int n = row >> 3, bl = row & 7;
      #pragma unroll
      for(int ft=0; ft<8; ft++){
        int f = 16*ft + c;
        outb[((size_t)(bl*4+(f>>5))*NN + n)*32 + (f&31)] = f2bf(acc[rt][ft][r] + bias[ft]);
      }
    }
  }
}

// ---------------- conv1d (MFMA, 32 rows/wave) + bias + residual(f32) + LN + relu ----------------
// LAST=false: write h (f32, m-layout) + Hb (region layout).  LAST=true: fused output projection.
template<bool LAST>
__global__ __launch_bounds__(256) void k_conv(const unsigned short* __restrict__ Cin,
                                              const unsigned short* __restrict__ Wvt,
                                              const float* __restrict__ cb, const float* __restrict__ lg,
                                              const float* __restrict__ lb,
                                              float* __restrict__ H, unsigned short* __restrict__ Hb,
                                              const float* __restrict__ ow, const float* __restrict__ ob,
                                              float* __restrict__ out, int b0){
  int t = threadIdx.x;
  int lane = t & 63, w = t >> 6;
  int c = lane & 15, g = lane >> 4;
  int rbase = blockIdx.x*128 + w*32;
  f32x4 acc[2][8];
  #pragma unroll
  for(int i=0;i<2;i++)
    #pragma unroll
    for(int j=0;j<8;j++) acc[i][j] = (f32x4){0.f,0.f,0.f,0.f};
  short8 zf = {0,0,0,0,0,0,0,0};
  for(int ic=0; ic<4; ic++){
    #pragma unroll
    for(int kw=0; kw<3; kw++){
      short8 af[2];
      #pragma unroll
      for(int rt=0; rt<2; rt++){
        int rowA = rbase + rt*16 + c + (kw-1)*BCK;   // node neighbor = m +/- BCK
        if((unsigned)rowA < (unsigned)NMC){
          int n = rowA >> 3, bl = rowA & 7;
          af[rt] = *(const short8*)(Cin + ((size_t)(bl*4+ic)*NN + n)*32 + 8*g);
        } else af[rt] = zf;
      }
      #pragma unroll
      for(int ft=0; ft<8; ft++){
        short8 bf_ = *(const short8*)(Wvt + (((size_t)kw*NH + 16*ft + c)<<7) + ic*32 + 8*g);
        #pragma unroll
        for(int rt=0; rt<2; rt++)
          acc[rt][ft] = __builtin_amdgcn_mfma_f32_16x16x32_bf16(af[rt], bf_, acc[rt][ft], 0, 0, 0);
      }
    }
  }
  float cbv[8], gv[8], bv[8];
  #pragma unroll
  for(int ft=0; ft<8; ft++){
    int f = 16*ft + c;
    cbv[ft] = cb[f]; gv[ft] = lg[f]; bv[ft] = lb[f];
  }
  #pragma unroll
  for(int rt=0; rt<2; rt++){
    #pragma unroll
    for(int r=0;r<4;r++){
      int row = rbase + rt*16 + 4*g + r;
      size_t rbs = (size_t)row*NH;
      int n = row >> 3, bl = row & 7;
      float vals[8];
      float s = 0.f;
      #pragma unroll
      for(int ft=0; ft<8; ft++){
        float res = H[rbs + 16*ft + c];
        float v = acc[rt][ft][r] + cbv[ft] + res;
        vals[ft] = v;
        s += v;
      }
      s += __shfl_xor(s,1,64); s += __shfl_xor(s,2,64);
      s += __shfl_xor(s,4,64); s += __shfl_xor(s,8,64);
      float mu = s * (1.f/128.f);
      float q = 0.f;
      #pragma unroll
      for(int ft=0; ft<8; ft++){ float d = vals[ft]-mu; q += d*d; }
      q += __shfl_xor(q,1,64); q += __shfl_xor(q,2,64);
      q += __shfl_xor(q,4,64); q += __shfl_xor(q,8,64);
      float rs = rsqrtf(q*(1.f/128.f) + EPSV);
      if(!LAST){
        #pragma unroll
        for(int ft=0; ft<8; ft++){
          float y = (vals[ft]-mu)*rs*gv[ft] + bv[ft];
          y = fmaxf(y, 0.f);
          H[rbs + 16*ft + c] = y;
          int f = 16*ft + c;
          Hb[((size_t)(bl*4+(f>>5))*NN + n)*32 + (f&31)] = f2bf(y);
        }
      } else {
        float p0=0.f, p1=0.f, p2=0.f;
        #pragma unroll
        for(int ft=0; ft<8; ft++){
          float y = (vals[ft]-mu)*rs*gv[ft] + bv[ft];
          y = fmaxf(y, 0.f);
          int f = 16*ft + c;
          p0 = fmaf(y, ow[f*3+0], p0);
          p1 = fmaf(y, ow[f*3+1], p1);
          p2 = fmaf(y, ow[f*3+2], p2);
        }
        p0 += __shfl_xor(p0,1,64); p0 += __shfl_xor(p0,2,64);
        p0 += __shfl_xor(p0,4,64); p0 += __shfl_xor(p0,8,64);
        p1 += __shfl_xor(p1,1,64); p1 += __shfl_xor(p1,2,64);
        p1 += __shfl_xor(p1,4,64); p1 += __shfl_xor(p1,8,64);
        p2 += __shfl_xor(p2,1,64); p2 += __shfl_xor(p2,2,64);
        p2 += __shfl_xor(p2,4,64); p2 += __shfl_xor(p2,8,64);
        if(c==0){
          int nn = row >> 3, bl2 = b0 + (row & 7);
          out[((size_t)bl2*NP+0)*NN+nn] = p0 + ob[0];
          out[((size_t)bl2*NP+1)*NN+nn] = p1 + ob[1];
          out[((size_t)bl2*NP+2)*NN+nn] = p2 + ob[2];
        }
      }
    }
  }
}

extern "C" void kernel_launch(void* const* d_in, const int* in_sizes, int n_in,
                              void* d_out, int out_size, void* d_ws, size_t ws_size,
                              hipStream_t stream) {
  const float* x      = (const float*)d_in[0];
  const int*   ei     = (const int*)d_in[1];
  const float* in_w   = (const float*)d_in[2];
  const float* in_b   = (const float*)d_in[3];
  const float* cheb_w = (const float*)d_in[4];
  const float* cheb_b = (const float*)d_in[5];
  const float* conv_w = (const float*)d_in[6];
  const float* conv_b = (const float*)d_in[7];
  const float* ln_g   = (const float*)d_in[8];
  const float* ln_b   = (const float*)d_in[9];
  const float* out_w  = (const float*)d_in[10];
  const float* out_b  = (const float*)d_in[11];
  float* out = (float*)d_out;

  char* ws = (char*)d_ws;
  size_t off = 0;
  auto alloc = [&](size_t bytes)->void*{
    void* p = ws + off;
    off += (bytes + 255) & ~(size_t)255;
    return p;
  };
  // ---- fixed region (~6.3 MB) ----
  int* flag    = (int*)alloc(4);
  int* deg     = (int*)alloc(NN*4);
  int* cnt     = (int*)alloc(NN*4);
  int* fill    = (int*)alloc(NN*4);
  int* offs    = (int*)alloc((NN+1)*4);
  float* dis   = (float*)alloc(NN*4);
  int2* edata  = (int2*)alloc((size_t)NE*8);
  unsigned short* Wct = (unsigned short*)alloc((size_t)NL*3*NH*NH*2);
  unsigned short* Wvt = (unsigned short*)alloc((size_t)NL*3*NH*NH*2);
  // ---- chunk activation buffers: 82 + 3*41 MB = 205 MB ----
  const size_t fullb = ((size_t)NMC*NH*4 + 255) & ~(size_t)255;
  const size_t halfb = ((size_t)NMC*NH*2 + 255) & ~(size_t)255;
  float*          h   = (float*)alloc(fullb);
  unsigned short* hb  = (unsigned short*)alloc(halfb);
  unsigned short* t1b = (unsigned short*)alloc(halfb);
  unsigned short* t2b = (unsigned short*)alloc(halfb);

  hipMemsetAsync(deg, 0, NN*4, stream);
  hipMemsetAsync(cnt, 0, NN*4, stream);
  hipMemsetAsync(fill, 0, NN*4, stream);

  k_detect<<<1,256,0,stream>>>(ei,flag);
  k_count<<<(NE+255)/256,256,0,stream>>>(ei,flag,deg,cnt);
  k_dis<<<(NN+255)/256,256,0,stream>>>(deg,dis);
  k_scan<<<1,1024,0,stream>>>(cnt,offs);
  k_scatter<<<(NE+255)/256,256,0,stream>>>(ei,flag,offs,fill,dis,edata);
  k_sortseg<<<NN,64,0,stream>>>(offs,edata);
  k_prepw<<<(NL*3*NH*NH+255)/256,256,0,stream>>>(cheb_w,conv_w,Wct,Wvt);

  for(int b0=0; b0<NB; b0+=BCK){
    k_inproj<<<NMC/4,256,0,stream>>>(x,in_w,in_b,h,(unsigned int*)hb,b0);
    for(int l=0;l<NL;l++){
      k_prop<false><<<NREG*NGPB,256,0,stream>>>((const uint4*)hb,  nullptr,
                                                (uint4*)t1b, offs, edata);
      k_prop<true ><<<NREG*NGPB,256,0,stream>>>((const uint4*)t1b, (const uint4*)hb,
                                                (uint4*)t2b, offs, edata);
      k_cheb<<<NGEMM,256,0,stream>>>(hb, t1b, t2b, Wct + (size_t)l*3*NH*NH,
                                     cheb_b + l*NH, t2b);
      if(l==0)
        k_conv<false><<<NGEMM,256,0,stream>>>(t2b, Wvt + (size_t)l*3*NH*NH, conv_b + l*NH,
                                              ln_g + l*NH, ln_b + l*NH, h, hb,
                                              out_w, out_b, out, b0);
      else
        k_conv<true ><<<NGEMM,256,0,stream>>>(t2b, Wvt + (size_t)l*3*NH*NH, conv_b + l*NH,
                                              ln_g + l*NH, ln_b + l*NH, h, hb,
                                              out_w, out_b, out, b0);
    }
  }
}

// Round 15
// 2036.850 us; speedup vs baseline: 1.0938x; 1.0309x over previous
//
#include <hip/hip_runtime.h>

#define NB 16
#define NS 12
#define NN 20000
#define NH 128
#define NP 3
#define NE 640000
#define NL 2
#define EPSV 1e-5f
#define BCK 8                 // batches per chunk
#define NMC (NN*BCK)          // 160000 rows per chunk (m = n*8 + bl)
#define NGEMM (NMC/256)       // 625 blocks for cheb/conv (256 rows per block, 64/wave)
#define NREG (BCK*4)          // 32 (batch,quarter) regions per chunk
#define NGPB 1250             // NN/16 node-groups per region (16 dsts/block)

typedef __attribute__((ext_vector_type(8))) short short8;
typedef __attribute__((ext_vector_type(4))) float f32x4;
typedef __attribute__((ext_vector_type(4))) unsigned int u32x4;

__device__ __forceinline__ unsigned short f2bf(float f){
  unsigned int x = __float_as_uint(f);
  unsigned int r = x + 0x7FFFu + ((x >> 16) & 1u);
  return (unsigned short)(r >> 16);
}
__device__ __forceinline__ unsigned int pack2(float a, float b){
  return (unsigned int)f2bf(a) | ((unsigned int)f2bf(b) << 16);
}
__device__ __forceinline__ float bflo(unsigned int u){ return __uint_as_float(u << 16); }
__device__ __forceinline__ float bfhi(unsigned int u){ return __uint_as_float(u & 0xFFFF0000u); }

// ---------------- edge dtype detect ----------------
__global__ void k_detect(const int* __restrict__ ei, int* __restrict__ flag){
  __shared__ int any;
  if(threadIdx.x==0) any=0;
  __syncthreads();
  int nz=0;
  for(int i=threadIdx.x;i<4096;i+=256) if(ei[2*i+1]!=0) nz=1;
  if(nz) atomicOr(&any,1);
  __syncthreads();
  if(threadIdx.x==0) *flag = any ? 0 : 1;   // 1 = int64 layout
}

// ---------------- graph preprocessing ----------------
__global__ void k_count(const int* __restrict__ ei, const int* __restrict__ flag,
                        int* __restrict__ deg_src, int* __restrict__ cnt_dst){
  int e = blockIdx.x*256+threadIdx.x;
  if(e<NE){
    int f = *flag;
    int s = f ? ei[2*e]        : ei[e];
    int d = f ? ei[2*NE + 2*e] : ei[NE+e];
    atomicAdd(&deg_src[s],1);
    atomicAdd(&cnt_dst[d],1);
  }
}

__global__ void k_dis(const int* __restrict__ deg, float* __restrict__ dis){
  int n = blockIdx.x*256+threadIdx.x;
  if(n<NN) dis[n] = deg[n]>0 ? rsqrtf((float)deg[n]) : 0.f;
}

__global__ __launch_bounds__(1024) void k_scan(const int* __restrict__ cnt, int* __restrict__ offs){
  __shared__ int warpsum[16];
  __shared__ int carry;
  if(threadIdx.x==0) carry=0;
  __syncthreads();
  int lane = threadIdx.x & 63, wid = threadIdx.x >> 6;
  for(int base=0;base<NN;base+=1024){
    int i = base+threadIdx.x;
    int v = (i<NN)?cnt[i]:0;
    int x = v;
    #pragma unroll
    for(int off=1;off<64;off<<=1){
      int y=__shfl_up(x,off,64);
      if(lane>=off) x+=y;
    }
    if(lane==63) warpsum[wid]=x;
    __syncthreads();
    if(wid==0){
      int w=(lane<16)?warpsum[lane]:0;
      #pragma unroll
      for(int off=1;off<16;off<<=1){
        int y=__shfl_up(w,off,64);
        if(lane>=off) w+=y;
      }
      if(lane<16) warpsum[lane]=w;
    }
    __syncthreads();
    int incl = x + ((wid>0)?warpsum[wid-1]:0) + carry;
    if(i<NN) offs[i]=incl-v;
    __syncthreads();
    if(threadIdx.x==1023) carry=incl;
    __syncthreads();
  }
  if(threadIdx.x==0) offs[NN]=carry;
}

__global__ void k_scatter(const int* __restrict__ ei, const int* __restrict__ flag,
                          const int* __restrict__ offs, int* __restrict__ fill,
                          const float* __restrict__ dis, int2* __restrict__ edata){
  int e = blockIdx.x*256+threadIdx.x;
  if(e<NE){
    int f = *flag;
    int s = f ? ei[2*e]        : ei[e];
    int d = f ? ei[2*NE + 2*e] : ei[NE+e];
    int pos = offs[d] + atomicAdd(&fill[d],1);
    edata[pos] = make_int2(s, (int)f2bf(-dis[s]*dis[d]));   // bf16 weight in low 16
  }
}

// ---------------- per-dst src-sort (deterministic rank sort; canonical order) ----------------
__global__ __launch_bounds__(64) void k_sortseg(const int* __restrict__ offs, int2* __restrict__ edata){
  __shared__ int2 seg[128];
  int v = blockIdx.x;
  int e0 = offs[v], e1 = offs[v+1], d = e1 - e0;
  int lane = threadIdx.x;
  if(d < 2 || d > 128) return;          // unsorted is still correct
  for(int i=lane; i<d; i+=64) seg[i] = edata[e0+i];
  __syncthreads();
  for(int i=lane; i<d; i+=64){
    int2 me = seg[i];
    int r = 0;
    for(int j=0; j<d; j++){
      int2 ot = seg[j];
      r += (ot.x < me.x) || (ot.x == me.x && j < i);
    }
    edata[e0 + r] = me;
  }
}

// weights -> bf16 B^T: Wct[l][tm][f][k] = cheb_w[l][tm][k][f];  Wvt[l][kw][f][i] = conv_w[l][f][i][kw]
__global__ void k_prepw(const float* __restrict__ cw, const float* __restrict__ vw,
                        unsigned short* __restrict__ Wct, unsigned short* __restrict__ Wvt){
  int idx = blockIdx.x*256+threadIdx.x;
  if(idx < NL*3*NH*NH){
    int k = idx & 127;
    int r = idx >> 7;
    int f = r & 127; r >>= 7;
    int sel = r % 3; int l = r / 3;
    Wct[idx] = f2bf(cw[(((l*3+sel)*NH + k)*NH) + f]);
    Wvt[idx] = f2bf(vw[((l*NH + f)*NH + k)*3 + sel]);
  }
}

// ---------------- input projection -> h (f32, m-layout) + hbq (bf16, region layout) ----------------
// region layout: [bl][q][n][32feats];  u32 row = 16 words
__global__ __launch_bounds__(256) void k_inproj(const float* __restrict__ x, const float* __restrict__ w,
                                                const float* __restrict__ bb, float* __restrict__ h,
                                                unsigned int* __restrict__ hbq, int b0){
  __shared__ float ws_[NS*NH];
  int t=threadIdx.x;
  for(int i=t;i<NS*NH;i+=256) ws_[i]=w[i];
  __syncthreads();
  int lane = t & 63;
  int m = blockIdx.x*4 + (t>>6);       // < NMC
  int n = m >> 3, bl = m & 7;
  const float* xp = x + (size_t)(b0+bl)*NS*NN + n;
  float a0 = bb[2*lane], a1 = bb[2*lane+1];
  #pragma unroll
  for(int s=0;s<NS;s++){
    float xv = xp[(size_t)s*NN];
    a0 = fmaf(xv, ws_[s*NH+2*lane],   a0);
    a1 = fmaf(xv, ws_[s*NH+2*lane+1], a1);
  }
  ((float2*)h)[(size_t)m*64 + lane] = make_float2(a0,a1);
  hbq[((size_t)(bl*4 + (lane>>4))*NN + n)*16 + (lane&15)] = pack2(a0,a1);
}

// ---------------- propagation: region-major grid, 16 dsts/block, dot2, 4-edge deep pipeline ----------------
#define DOT2(ACC,AB,WP) asm("v_dot2_f32_bf16 %0, %1, %2, %0" : "+v"(ACC) : "v"(AB), "v"(WP))

template<bool COMBINE>
__global__ __launch_bounds__(256) void k_prop(const uint4* __restrict__ in, const uint4* __restrict__ sub,
                                              uint4* __restrict__ outp, const int* __restrict__ offs,
                                              const int2* __restrict__ edata){
  int b = blockIdx.x;
  int region = b / NGPB;               // sequential in dispatch order
  int ng = b % NGPB;
  int t = threadIdx.x;
  int dst = ng*16 + (t>>4);
  int ep = (t>>2)&3, sl = t&3;
  const uint4* base = in + (size_t)region*NN*4;
  int e0 = offs[dst] + ep, e1 = offs[dst+1];
  float a0=0.f,a1=0.f,a2=0.f,a3=0.f,a4=0.f,a5=0.f,a6=0.f,a7=0.f;
  int e = e0;
  unsigned int lo, hi;
  // 4 edges per lane-iteration: all loads issued before any consumption (2x MLP)
  for(; e+12 < e1; e += 16){
    int2 m0 = edata[e], m1 = edata[e+4], m2 = edata[e+8], m3 = edata[e+12];
    uint4 p0 = base[(size_t)m0.x*4 + sl];
    uint4 p1 = base[(size_t)m1.x*4 + sl];
    uint4 p2 = base[(size_t)m2.x*4 + sl];
    uint4 p3 = base[(size_t)m3.x*4 + sl];
    unsigned int wpA = ((unsigned int)m0.y & 0xFFFFu) | ((unsigned int)m1.y << 16);
    unsigned int wpB = ((unsigned int)m2.y & 0xFFFFu) | ((unsigned int)m3.y << 16);
    lo = __builtin_amdgcn_perm(p1.x, p0.x, 0x05040100u);
    hi = __builtin_amdgcn_perm(p1.x, p0.x, 0x07060302u);
    DOT2(a0, lo, wpA); DOT2(a1, hi, wpA);
    lo = __builtin_amdgcn_perm(p1.y, p0.y, 0x05040100u);
    hi = __builtin_amdgcn_perm(p1.y, p0.y, 0x07060302u);
    DOT2(a2, lo, wpA); DOT2(a3, hi, wpA);
    lo = __builtin_amdgcn_perm(p1.z, p0.z, 0x05040100u);
    hi = __builtin_amdgcn_perm(p1.z, p0.z, 0x07060302u);
    DOT2(a4, lo, wpA); DOT2(a5, hi, wpA);
    lo = __builtin_amdgcn_perm(p1.w, p0.w, 0x05040100u);
    hi = __builtin_amdgcn_perm(p1.w, p0.w, 0x07060302u);
    DOT2(a6, lo, wpA); DOT2(a7, hi, wpA);
    lo = __builtin_amdgcn_perm(p3.x, p2.x, 0x05040100u);
    hi = __builtin_amdgcn_perm(p3.x, p2.x, 0x07060302u);
    DOT2(a0, lo, wpB); DOT2(a1, hi, wpB);
    lo = __builtin_amdgcn_perm(p3.y, p2.y, 0x05040100u);
    hi = __builtin_amdgcn_perm(p3.y, p2.y, 0x07060302u);
    DOT2(a2, lo, wpB); DOT2(a3, hi, wpB);
    lo = __builtin_amdgcn_perm(p3.z, p2.z, 0x05040100u);
    hi = __builtin_amdgcn_perm(p3.z, p2.z, 0x07060302u);
    DOT2(a4, lo, wpB); DOT2(a5, hi, wpB);
    lo = __builtin_amdgcn_perm(p3.w, p2.w, 0x05040100u);
    hi = __builtin_amdgcn_perm(p3.w, p2.w, 0x07060302u);
    DOT2(a6, lo, wpB); DOT2(a7, hi, wpB);
  }
  for(; e+4 < e1; e += 8){
    int2 m0 = edata[e], m1 = edata[e+4];
    uint4 p0 = base[(size_t)m0.x*4 + sl];
    uint4 p1 = base[(size_t)m1.x*4 + sl];
    unsigned int wp = ((unsigned int)m0.y & 0xFFFFu) | ((unsigned int)m1.y << 16);
    lo = __builtin_amdgcn_perm(p1.x, p0.x, 0x05040100u);
    hi = __builtin_amdgcn_perm(p1.x, p0.x, 0x07060302u);
    DOT2(a0, lo, wp); DOT2(a1, hi, wp);
    lo = __builtin_amdgcn_perm(p1.y, p0.y, 0x05040100u);
    hi = __builtin_amdgcn_perm(p1.y, p0.y, 0x07060302u);
    DOT2(a2, lo, wp); DOT2(a3, hi, wp);
    lo = __builtin_amdgcn_perm(p1.z, p0.z, 0x05040100u);
    hi = __builtin_amdgcn_perm(p1.z, p0.z, 0x07060302u);
    DOT2(a4, lo, wp); DOT2(a5, hi, wp);
    lo = __builtin_amdgcn_perm(p1.w, p0.w, 0x05040100u);
    hi = __builtin_amdgcn_perm(p1.w, p0.w, 0x07060302u);
    DOT2(a6, lo, wp); DOT2(a7, hi, wp);
  }
  if(e < e1){
    int2 m = edata[e];
    uint4 p = base[(size_t)m.x*4 + sl];
    float w = __uint_as_float(((unsigned int)m.y) << 16);
    a0=fmaf(w,bflo(p.x),a0); a1=fmaf(w,bfhi(p.x),a1);
    a2=fmaf(w,bflo(p.y),a2); a3=fmaf(w,bfhi(p.y),a3);
    a4=fmaf(w,bflo(p.z),a4); a5=fmaf(w,bfhi(p.z),a5);
    a6=fmaf(w,bflo(p.w),a6); a7=fmaf(w,bfhi(p.w),a7);
  }
  a0+=__shfl_xor(a0,4,64); a1+=__shfl_xor(a1,4,64); a2+=__shfl_xor(a2,4,64); a3+=__shfl_xor(a3,4,64);
  a4+=__shfl_xor(a4,4,64); a5+=__shfl_xor(a5,4,64); a6+=__shfl_xor(a6,4,64); a7+=__shfl_xor(a7,4,64);
  a0+=__shfl_xor(a0,8,64); a1+=__shfl_xor(a1,8,64); a2+=__shfl_xor(a2,8,64); a3+=__shfl_xor(a3,8,64);
  a4+=__shfl_xor(a4,8,64); a5+=__shfl_xor(a5,8,64); a6+=__shfl_xor(a6,8,64); a7+=__shfl_xor(a7,8,64);
  if(ep==0){
    size_t o = (size_t)region*NN*4 + (size_t)dst*4 + sl;
    if(COMBINE){
      uint4 hv = sub[o];
      a0 = 2.f*a0 - bflo(hv.x); a1 = 2.f*a1 - bfhi(hv.x);
      a2 = 2.f*a2 - bflo(hv.y); a3 = 2.f*a3 - bfhi(hv.y);
      a4 = 2.f*a4 - bflo(hv.z); a5 = 2.f*a5 - bfhi(hv.z);
      a6 = 2.f*a6 - bflo(hv.w); a7 = 2.f*a7 - bfhi(hv.w);
    }
    uint4 r;
    r.x = pack2(a0,a1); r.y = pack2(a2,a3); r.z = pack2(a4,a5); r.w = pack2(a6,a7);
    outp[o] = r;
  }
}

// ---------------- cheb matmul (MFMA, 64 rows/wave), region-layout activations ----------------
__global__ __launch_bounds__(256) void k_cheb(const unsigned short* __restrict__ T0,
                                              const unsigned short* __restrict__ T1,
                                              const unsigned short* __restrict__ T2,
                                              const unsigned short* __restrict__ Wct,
                                              const float* __restrict__ cb,
                                              unsigned short* __restrict__ outb){
  int t = threadIdx.x;
  int lane = t & 63, w = t >> 6;
  int c = lane & 15, g = lane >> 4;
  int rbase = blockIdx.x*256 + w*64;
  const unsigned short* Ts[3] = {T0, T1, T2};
  f32x4 acc[4][8];
  #pragma unroll
  for(int i=0;i<4;i++)
    #pragma unroll
    for(int j=0;j<8;j++) acc[i][j] = (f32x4){0.f,0.f,0.f,0.f};
  for(int kc=0; kc<4; kc++){
    #pragma unroll
    for(int tm=0; tm<3; tm++){
      short8 af[4];
      #pragma unroll
      for(int rt=0; rt<4; rt++){
        int m = rbase + rt*16 + c;
        int n = m >> 3, bl = m & 7;
        af[rt] = *(const short8*)(Ts[tm] + ((size_t)(bl*4+kc)*NN + n)*32 + 8*g);
      }
      #pragma unroll
      for(int ft=0; ft<8; ft++){
        short8 bf_ = *(const short8*)(Wct + (((size_t)tm*NH + 16*ft + c)<<7) + kc*32 + 8*g);
        #pragma unroll
        for(int rt=0; rt<4; rt++)
          acc[rt][ft] = __builtin_amdgcn_mfma_f32_16x16x32_bf16(af[rt], bf_, acc[rt][ft], 0, 0, 0);
      }
    }
  }
  float bias[8];
  #pragma unroll
  for(int ft=0; ft<8; ft++) bias[ft] = cb[16*ft + c];
  #pragma unroll
  for(int rt=0; rt<4; rt++){
    #pragma unroll
    for(int r=0;r<4;r++){
      int row = rbase + rt*16 + 4*g + r;
      int n = row >> 3, bl = row & 7;
      #pragma unroll
      for(int ft=0; ft<8; ft++){
        int f = 16*ft + c;
        outb[((size_t)(bl*4+(f>>5))*NN + n)*32 + (f&31)] = f2bf(acc[rt][ft][r] + bias[ft]);
      }
    }
  }
}

// ---------------- conv1d (MFMA, 64 rows/wave) + bias + residual(f32) + LN + relu ----------------
// LAST=false: write h (f32, m-layout) + Hb (region layout).  LAST=true: fused output projection.
template<bool LAST>
__global__ __launch_bounds__(256) void k_conv(const unsigned short* __restrict__ Cin,
                                              const unsigned short* __restrict__ Wvt,
                                              const float* __restrict__ cb, const float* __restrict__ lg,
                                              const float* __restrict__ lb,
                                              float* __restrict__ H, unsigned short* __restrict__ Hb,
                                              const float* __restrict__ ow, const float* __restrict__ ob,
                                              float* __restrict__ out, int b0){
  int t = threadIdx.x;
  int lane = t & 63, w = t >> 6;
  int c = lane & 15, g = lane >> 4;
  int rbase = blockIdx.x*256 + w*64;
  f32x4 acc[4][8];
  #pragma unroll
  for(int i=0;i<4;i++)
    #pragma unroll
    for(int j=0;j<8;j++) acc[i][j] = (f32x4){0.f,0.f,0.f,0.f};
  short8 zf = {0,0,0,0,0,0,0,0};
  for(int ic=0; ic<4; ic++){
    #pragma unroll
    for(int kw=0; kw<3; kw++){
      short8 af[4];
      #pragma unroll
      for(int rt=0; rt<4; rt++){
        int rowA = rbase + rt*16 + c + (kw-1)*BCK;   // node neighbor = m +/- BCK
        if((unsigned)rowA < (unsigned)NMC){
          int n = rowA >> 3, bl = rowA & 7;
          af[rt] = *(const short8*)(Cin + ((size_t)(bl*4+ic)*NN + n)*32 + 8*g);
        } else af[rt] = zf;
      }
      #pragma unroll
      for(int ft=0; ft<8; ft++){
        short8 bf_ = *(const short8*)(Wvt + (((size_t)kw*NH + 16*ft + c)<<7) + ic*32 + 8*g);
        #pragma unroll
        for(int rt=0; rt<4; rt++)
          acc[rt][ft] = __builtin_amdgcn_mfma_f32_16x16x32_bf16(af[rt], bf_, acc[rt][ft], 0, 0, 0);
      }
    }
  }
  float cbv[8], gv[8], bv[8];
  #pragma unroll
  for(int ft=0; ft<8; ft++){
    int f = 16*ft + c;
    cbv[ft] = cb[f]; gv[ft] = lg[f]; bv[ft] = lb[f];
  }
  #pragma unroll
  for(int rt=0; rt<4; rt++){
    #pragma unroll
    for(int r=0;r<4;r++){
      int row = rbase + rt*16 + 4*g + r;
      size_t rbs = (size_t)row*NH;
      int n = row >> 3, bl = row & 7;
      float vals[8];
      float s = 0.f;
      #pragma unroll
      for(int ft=0; ft<8; ft++){
        float res = H[rbs + 16*ft + c];
        float v = acc[rt][ft][r] + cbv[ft] + res;
        vals[ft] = v;
        s += v;
      }
      s += __shfl_xor(s,1,64); s += __shfl_xor(s,2,64);
      s += __shfl_xor(s,4,64); s += __shfl_xor(s,8,64);
      float mu = s * (1.f/128.f);
      float q = 0.f;
      #pragma unroll
      for(int ft=0; ft<8; ft++){ float d = vals[ft]-mu; q += d*d; }
      q += __shfl_xor(q,1,64); q += __shfl_xor(q,2,64);
      q += __shfl_xor(q,4,64); q += __shfl_xor(q,8,64);
      float rs = rsqrtf(q*(1.f/128.f) + EPSV);
      if(!LAST){
        #pragma unroll
        for(int ft=0; ft<8; ft++){
          float y = (vals[ft]-mu)*rs*gv[ft] + bv[ft];
          y = fmaxf(y, 0.f);
          H[rbs + 16*ft + c] = y;
          int f = 16*ft + c;
          Hb[((size_t)(bl*4+(f>>5))*NN + n)*32 + (f&31)] = f2bf(y);
        }
      } else {
        float p0=0.f, p1=0.f, p2=0.f;
        #pragma unroll
        for(int ft=0; ft<8; ft++){
          float y = (vals[ft]-mu)*rs*gv[ft] + bv[ft];
          y = fmaxf(y, 0.f);
          int f = 16*ft + c;
          p0 = fmaf(y, ow[f*3+0], p0);
          p1 = fmaf(y, ow[f*3+1], p1);
          p2 = fmaf(y, ow[f*3+2], p2);
        }
        p0 += __shfl_xor(p0,1,64); p0 += __shfl_xor(p0,2,64);
        p0 += __shfl_xor(p0,4,64); p0 += __shfl_xor(p0,8,64);
        p1 += __shfl_xor(p1,1,64); p1 += __shfl_xor(p1,2,64);
        p1 += __shfl_xor(p1,4,64); p1 += __shfl_xor(p1,8,64);
        p2 += __shfl_xor(p2,1,64); p2 += __shfl_xor(p2,2,64);
        p2 += __shfl_xor(p2,4,64); p2 += __shfl_xor(p2,8,64);
        if(c==0){
          int nn = row >> 3, bl2 = b0 + (row & 7);
          out[((size_t)bl2*NP+0)*NN+nn] = p0 + ob[0];
          out[((size_t)bl2*NP+1)*NN+nn] = p1 + ob[1];
          out[((size_t)bl2*NP+2)*NN+nn] = p2 + ob[2];
        }
      }
    }
  }
}

extern "C" void kernel_launch(void* const* d_in, const int* in_sizes, int n_in,
                              void* d_out, int out_size, void* d_ws, size_t ws_size,
                              hipStream_t stream) {
  const float* x      = (const float*)d_in[0];
  const int*   ei     = (const int*)d_in[1];
  const float* in_w   = (const float*)d_in[2];
  const float* in_b   = (const float*)d_in[3];
  const float* cheb_w = (const float*)d_in[4];
  const float* cheb_b = (const float*)d_in[5];
  const float* conv_w = (const float*)d_in[6];
  const float* conv_b = (const float*)d_in[7];
  const float* ln_g   = (const float*)d_in[8];
  const float* ln_b   = (const float*)d_in[9];
  const float* out_w  = (const float*)d_in[10];
  const float* out_b  = (const float*)d_in[11];
  float* out = (float*)d_out;

  char* ws = (char*)d_ws;
  size_t off = 0;
  auto alloc = [&](size_t bytes)->void*{
    void* p = ws + off;
    off += (bytes + 255) & ~(size_t)255;
    return p;
  };
  // ---- fixed region (~6.3 MB) ----
  int* flag    = (int*)alloc(4);
  int* deg     = (int*)alloc(NN*4);
  int* cnt     = (int*)alloc(NN*4);
  int* fill    = (int*)alloc(NN*4);
  int* offs    = (int*)alloc((NN+1)*4);
  float* dis   = (float*)alloc(NN*4);
  int2* edata  = (int2*)alloc((size_t)NE*8);
  unsigned short* Wct = (unsigned short*)alloc((size_t)NL*3*NH*NH*2);
  unsigned short* Wvt = (unsigned short*)alloc((size_t)NL*3*NH*NH*2);
  // ---- chunk activation buffers: 82 + 3*41 MB = 205 MB ----
  const size_t fullb = ((size_t)NMC*NH*4 + 255) & ~(size_t)255;
  const size_t halfb = ((size_t)NMC*NH*2 + 255) & ~(size_t)255;
  float*          h   = (float*)alloc(fullb);
  unsigned short* hb  = (unsigned short*)alloc(halfb);
  unsigned short* t1b = (unsigned short*)alloc(halfb);
  unsigned short* t2b = (unsigned short*)alloc(halfb);

  hipMemsetAsync(deg, 0, NN*4, stream);
  hipMemsetAsync(cnt, 0, NN*4, stream);
  hipMemsetAsync(fill, 0, NN*4, stream);

  k_detect<<<1,256,0,stream>>>(ei,flag);
  k_count<<<(NE+255)/256,256,0,stream>>>(ei,flag,deg,cnt);
  k_dis<<<(NN+255)/256,256,0,stream>>>(deg,dis);
  k_scan<<<1,1024,0,stream>>>(cnt,offs);
  k_scatter<<<(NE+255)/256,256,0,stream>>>(ei,flag,offs,fill,dis,edata);
  k_sortseg<<<NN,64,0,stream>>>(offs,edata);
  k_prepw<<<(NL*3*NH*NH+255)/256,256,0,stream>>>(cheb_w,conv_w,Wct,Wvt);

  for(int b0=0; b0<NB; b0+=BCK){
    k_inproj<<<NMC/4,256,0,stream>>>(x,in_w,in_b,h,(unsigned int*)hb,b0);
    for(int l=0;l<NL;l++){
      k_prop<false><<<NREG*NGPB,256,0,stream>>>((const uint4*)hb,  nullptr,
                                                (uint4*)t1b, offs, edata);
      k_prop<true ><<<NREG*NGPB,256,0,stream>>>((const uint4*)t1b, (const uint4*)hb,
                                                (uint4*)t2b, offs, edata);
      k_cheb<<<NGEMM,256,0,stream>>>(hb, t1b, t2b, Wct + (size_t)l*3*NH*NH,
                                     cheb_b + l*NH, t2b);
      if(l==0)
        k_conv<false><<<NGEMM,256,0,stream>>>(t2b, Wvt + (size_t)l*3*NH*NH, conv_b + l*NH,
                                              ln_g + l*NH, ln_b + l*NH, h, hb,
                                              out_w, out_b, out, b0);
      else
        k_conv<true ><<<NGEMM,256,0,stream>>>(t2b, Wvt + (size_t)l*3*NH*NH, conv_b + l*NH,
                                              ln_g + l*NH, ln_b + l*NH, h, hb,
                                              out_w, out_b, out, b0);
    }
  }
}

// Round 16
// 1914.814 us; speedup vs baseline: 1.1635x; 1.0637x over previous
//
#include <hip/hip_runtime.h>

#define NB 16
#define NS 12
#define NN 20000
#define NH 128
#define NP 3
#define NE 640000
#define NL 2
#define EPSV 1e-5f
#define BCK 8                 // batches per chunk
#define NMC (NN*BCK)          // 160000 rows per chunk (m = n*8 + bl)
#define NGEMM (NMC/256)       // 625 blocks for cheb/conv (256 rows per block, 64/wave)
#define NREG (BCK*4)          // 32 (batch,quarter) regions per chunk
#define NGPB 1250             // NN/16 node-groups per region (16 dsts/block)

typedef __attribute__((ext_vector_type(8))) short short8;
typedef __attribute__((ext_vector_type(4))) float f32x4;
typedef __attribute__((ext_vector_type(4))) unsigned int u32x4;

__device__ __forceinline__ unsigned short f2bf(float f){
  unsigned int x = __float_as_uint(f);
  unsigned int r = x + 0x7FFFu + ((x >> 16) & 1u);
  return (unsigned short)(r >> 16);
}
__device__ __forceinline__ unsigned int pack2(float a, float b){
  return (unsigned int)f2bf(a) | ((unsigned int)f2bf(b) << 16);
}
__device__ __forceinline__ float bflo(unsigned int u){ return __uint_as_float(u << 16); }
__device__ __forceinline__ float bfhi(unsigned int u){ return __uint_as_float(u & 0xFFFF0000u); }

// ---------------- edge dtype detect ----------------
__global__ void k_detect(const int* __restrict__ ei, int* __restrict__ flag){
  __shared__ int any;
  if(threadIdx.x==0) any=0;
  __syncthreads();
  int nz=0;
  for(int i=threadIdx.x;i<4096;i+=256) if(ei[2*i+1]!=0) nz=1;
  if(nz) atomicOr(&any,1);
  __syncthreads();
  if(threadIdx.x==0) *flag = any ? 0 : 1;   // 1 = int64 layout
}

// ---------------- graph preprocessing ----------------
__global__ void k_count(const int* __restrict__ ei, const int* __restrict__ flag,
                        int* __restrict__ deg_src, int* __restrict__ cnt_dst){
  int e = blockIdx.x*256+threadIdx.x;
  if(e<NE){
    int f = *flag;
    int s = f ? ei[2*e]        : ei[e];
    int d = f ? ei[2*NE + 2*e] : ei[NE+e];
    atomicAdd(&deg_src[s],1);
    atomicAdd(&cnt_dst[d],1);
  }
}

__global__ void k_dis(const int* __restrict__ deg, float* __restrict__ dis){
  int n = blockIdx.x*256+threadIdx.x;
  if(n<NN) dis[n] = deg[n]>0 ? rsqrtf((float)deg[n]) : 0.f;
}

__global__ __launch_bounds__(1024) void k_scan(const int* __restrict__ cnt, int* __restrict__ offs){
  __shared__ int warpsum[16];
  __shared__ int carry;
  if(threadIdx.x==0) carry=0;
  __syncthreads();
  int lane = threadIdx.x & 63, wid = threadIdx.x >> 6;
  for(int base=0;base<NN;base+=1024){
    int i = base+threadIdx.x;
    int v = (i<NN)?cnt[i]:0;
    int x = v;
    #pragma unroll
    for(int off=1;off<64;off<<=1){
      int y=__shfl_up(x,off,64);
      if(lane>=off) x+=y;
    }
    if(lane==63) warpsum[wid]=x;
    __syncthreads();
    if(wid==0){
      int w=(lane<16)?warpsum[lane]:0;
      #pragma unroll
      for(int off=1;off<16;off<<=1){
        int y=__shfl_up(w,off,64);
        if(lane>=off) w+=y;
      }
      if(lane<16) warpsum[lane]=w;
    }
    __syncthreads();
    int incl = x + ((wid>0)?warpsum[wid-1]:0) + carry;
    if(i<NN) offs[i]=incl-v;
    __syncthreads();
    if(threadIdx.x==1023) carry=incl;
    __syncthreads();
  }
  if(threadIdx.x==0) offs[NN]=carry;
}

__global__ void k_scatter(const int* __restrict__ ei, const int* __restrict__ flag,
                          const int* __restrict__ offs, int* __restrict__ fill,
                          const float* __restrict__ dis, int2* __restrict__ edata){
  int e = blockIdx.x*256+threadIdx.x;
  if(e<NE){
    int f = *flag;
    int s = f ? ei[2*e]        : ei[e];
    int d = f ? ei[2*NE + 2*e] : ei[NE+e];
    int pos = offs[d] + atomicAdd(&fill[d],1);
    edata[pos] = make_int2(s, (int)f2bf(-dis[s]*dis[d]));   // bf16 weight in low 16
  }
}

// ---------------- per-dst src-sort (deterministic rank sort; canonical order) ----------------
__global__ __launch_bounds__(64) void k_sortseg(const int* __restrict__ offs, int2* __restrict__ edata){
  __shared__ int2 seg[128];
  int v = blockIdx.x;
  int e0 = offs[v], e1 = offs[v+1], d = e1 - e0;
  int lane = threadIdx.x;
  if(d < 2 || d > 128) return;          // unsorted is still correct
  for(int i=lane; i<d; i+=64) seg[i] = edata[e0+i];
  __syncthreads();
  for(int i=lane; i<d; i+=64){
    int2 me = seg[i];
    int r = 0;
    for(int j=0; j<d; j++){
      int2 ot = seg[j];
      r += (ot.x < me.x) || (ot.x == me.x && j < i);
    }
    edata[e0 + r] = me;
  }
}

// weights -> bf16 B^T: Wct[l][tm][f][k] = cheb_w[l][tm][k][f];  Wvt[l][kw][f][i] = conv_w[l][f][i][kw]
__global__ void k_prepw(const float* __restrict__ cw, const float* __restrict__ vw,
                        unsigned short* __restrict__ Wct, unsigned short* __restrict__ Wvt){
  int idx = blockIdx.x*256+threadIdx.x;
  if(idx < NL*3*NH*NH){
    int k = idx & 127;
    int r = idx >> 7;
    int f = r & 127; r >>= 7;
    int sel = r % 3; int l = r / 3;
    Wct[idx] = f2bf(cw[(((l*3+sel)*NH + k)*NH) + f]);
    Wvt[idx] = f2bf(vw[((l*NH + f)*NH + k)*3 + sel]);
  }
}

// ---------------- input projection -> h (f32, m-layout) + hbq (bf16, region layout) ----------------
// region layout: [bl][q][n][32feats];  u32 row = 16 words
__global__ __launch_bounds__(256) void k_inproj(const float* __restrict__ x, const float* __restrict__ w,
                                                const float* __restrict__ bb, float* __restrict__ h,
                                                unsigned int* __restrict__ hbq, int b0){
  __shared__ float ws_[NS*NH];
  int t=threadIdx.x;
  for(int i=t;i<NS*NH;i+=256) ws_[i]=w[i];
  __syncthreads();
  int lane = t & 63;
  int m = blockIdx.x*4 + (t>>6);       // < NMC
  int n = m >> 3, bl = m & 7;
  const float* xp = x + (size_t)(b0+bl)*NS*NN + n;
  float a0 = bb[2*lane], a1 = bb[2*lane+1];
  #pragma unroll
  for(int s=0;s<NS;s++){
    float xv = xp[(size_t)s*NN];
    a0 = fmaf(xv, ws_[s*NH+2*lane],   a0);
    a1 = fmaf(xv, ws_[s*NH+2*lane+1], a1);
  }
  ((float2*)h)[(size_t)m*64 + lane] = make_float2(a0,a1);
  hbq[((size_t)(bl*4 + (lane>>4))*NN + n)*16 + (lane&15)] = pack2(a0,a1);
}

// ---------------- propagation: region-major grid, 16 dsts/block, dot2, 4-edge deep pipeline ----------------
#define DOT2(ACC,AB,WP) asm("v_dot2_f32_bf16 %0, %1, %2, %0" : "+v"(ACC) : "v"(AB), "v"(WP))

template<bool COMBINE>
__global__ __launch_bounds__(256) void k_prop(const uint4* __restrict__ in, const uint4* __restrict__ sub,
                                              uint4* __restrict__ outp, const int* __restrict__ offs,
                                              const int2* __restrict__ edata){
  int b = blockIdx.x;
  int region = b / NGPB;               // sequential in dispatch order
  int ng = b % NGPB;
  int t = threadIdx.x;
  int dst = ng*16 + (t>>4);
  int ep = (t>>2)&3, sl = t&3;
  const uint4* base = in + (size_t)region*NN*4;
  int e0 = offs[dst] + ep, e1 = offs[dst+1];
  float a0=0.f,a1=0.f,a2=0.f,a3=0.f,a4=0.f,a5=0.f,a6=0.f,a7=0.f;
  int e = e0;
  unsigned int lo, hi;
  for(; e+12 < e1; e += 16){
    int2 m0 = edata[e], m1 = edata[e+4], m2 = edata[e+8], m3 = edata[e+12];
    uint4 p0 = base[(size_t)m0.x*4 + sl];
    uint4 p1 = base[(size_t)m1.x*4 + sl];
    uint4 p2 = base[(size_t)m2.x*4 + sl];
    uint4 p3 = base[(size_t)m3.x*4 + sl];
    unsigned int wpA = ((unsigned int)m0.y & 0xFFFFu) | ((unsigned int)m1.y << 16);
    unsigned int wpB = ((unsigned int)m2.y & 0xFFFFu) | ((unsigned int)m3.y << 16);
    lo = __builtin_amdgcn_perm(p1.x, p0.x, 0x05040100u);
    hi = __builtin_amdgcn_perm(p1.x, p0.x, 0x07060302u);
    DOT2(a0, lo, wpA); DOT2(a1, hi, wpA);
    lo = __builtin_amdgcn_perm(p1.y, p0.y, 0x05040100u);
    hi = __builtin_amdgcn_perm(p1.y, p0.y, 0x07060302u);
    DOT2(a2, lo, wpA); DOT2(a3, hi, wpA);
    lo = __builtin_amdgcn_perm(p1.z, p0.z, 0x05040100u);
    hi = __builtin_amdgcn_perm(p1.z, p0.z, 0x07060302u);
    DOT2(a4, lo, wpA); DOT2(a5, hi, wpA);
    lo = __builtin_amdgcn_perm(p1.w, p0.w, 0x05040100u);
    hi = __builtin_amdgcn_perm(p1.w, p0.w, 0x07060302u);
    DOT2(a6, lo, wpA); DOT2(a7, hi, wpA);
    lo = __builtin_amdgcn_perm(p3.x, p2.x, 0x05040100u);
    hi = __builtin_amdgcn_perm(p3.x, p2.x, 0x07060302u);
    DOT2(a0, lo, wpB); DOT2(a1, hi, wpB);
    lo = __builtin_amdgcn_perm(p3.y, p2.y, 0x05040100u);
    hi = __builtin_amdgcn_perm(p3.y, p2.y, 0x07060302u);
    DOT2(a2, lo, wpB); DOT2(a3, hi, wpB);
    lo = __builtin_amdgcn_perm(p3.z, p2.z, 0x05040100u);
    hi = __builtin_amdgcn_perm(p3.z, p2.z, 0x07060302u);
    DOT2(a4, lo, wpB); DOT2(a5, hi, wpB);
    lo = __builtin_amdgcn_perm(p3.w, p2.w, 0x05040100u);
    hi = __builtin_amdgcn_perm(p3.w, p2.w, 0x07060302u);
    DOT2(a6, lo, wpB); DOT2(a7, hi, wpB);
  }
  for(; e+4 < e1; e += 8){
    int2 m0 = edata[e], m1 = edata[e+4];
    uint4 p0 = base[(size_t)m0.x*4 + sl];
    uint4 p1 = base[(size_t)m1.x*4 + sl];
    unsigned int wp = ((unsigned int)m0.y & 0xFFFFu) | ((unsigned int)m1.y << 16);
    lo = __builtin_amdgcn_perm(p1.x, p0.x, 0x05040100u);
    hi = __builtin_amdgcn_perm(p1.x, p0.x, 0x07060302u);
    DOT2(a0, lo, wp); DOT2(a1, hi, wp);
    lo = __builtin_amdgcn_perm(p1.y, p0.y, 0x05040100u);
    hi = __builtin_amdgcn_perm(p1.y, p0.y, 0x07060302u);
    DOT2(a2, lo, wp); DOT2(a3, hi, wp);
    lo = __builtin_amdgcn_perm(p1.z, p0.z, 0x05040100u);
    hi = __builtin_amdgcn_perm(p1.z, p0.z, 0x07060302u);
    DOT2(a4, lo, wp); DOT2(a5, hi, wp);
    lo = __builtin_amdgcn_perm(p1.w, p0.w, 0x05040100u);
    hi = __builtin_amdgcn_perm(p1.w, p0.w, 0x07060302u);
    DOT2(a6, lo, wp); DOT2(a7, hi, wp);
  }
  if(e < e1){
    int2 m = edata[e];
    uint4 p = base[(size_t)m.x*4 + sl];
    float w = __uint_as_float(((unsigned int)m.y) << 16);
    a0=fmaf(w,bflo(p.x),a0); a1=fmaf(w,bfhi(p.x),a1);
    a2=fmaf(w,bflo(p.y),a2); a3=fmaf(w,bfhi(p.y),a3);
    a4=fmaf(w,bflo(p.z),a4); a5=fmaf(w,bfhi(p.z),a5);
    a6=fmaf(w,bflo(p.w),a6); a7=fmaf(w,bfhi(p.w),a7);
  }
  a0+=__shfl_xor(a0,4,64); a1+=__shfl_xor(a1,4,64); a2+=__shfl_xor(a2,4,64); a3+=__shfl_xor(a3,4,64);
  a4+=__shfl_xor(a4,4,64); a5+=__shfl_xor(a5,4,64); a6+=__shfl_xor(a6,4,64); a7+=__shfl_xor(a7,4,64);
  a0+=__shfl_xor(a0,8,64); a1+=__shfl_xor(a1,8,64); a2+=__shfl_xor(a2,8,64); a3+=__shfl_xor(a3,8,64);
  a4+=__shfl_xor(a4,8,64); a5+=__shfl_xor(a5,8,64); a6+=__shfl_xor(a6,8,64); a7+=__shfl_xor(a7,8,64);
  if(ep==0){
    size_t o = (size_t)region*NN*4 + (size_t)dst*4 + sl;
    if(COMBINE){
      uint4 hv = sub[o];
      a0 = 2.f*a0 - bflo(hv.x); a1 = 2.f*a1 - bfhi(hv.x);
      a2 = 2.f*a2 - bflo(hv.y); a3 = 2.f*a3 - bfhi(hv.y);
      a4 = 2.f*a4 - bflo(hv.z); a5 = 2.f*a5 - bfhi(hv.z);
      a6 = 2.f*a6 - bflo(hv.w); a7 = 2.f*a7 - bfhi(hv.w);
    }
    uint4 r;
    r.x = pack2(a0,a1); r.y = pack2(a2,a3); r.z = pack2(a4,a5); r.w = pack2(a6,a7);
    outp[o] = r;
  }
}

// ---- LDS B-panel helpers: [128 rows][40 halves] padded, rotation swizzle slot=(g+row)&3 ----
__device__ __forceinline__ void stageB(const unsigned short* __restrict__ src,
                                       unsigned short* __restrict__ dstbuf, int t){
  // src points at slice base: row f occupies src[f*128 .. f*128+31] (32 halves, k-local 0..31)
  int f = t >> 1, hb = t & 1;          // 2 threads per row, 16 halves (32B) each
  const uint4* sp = (const uint4*)(src + (size_t)f*NH + hb*16);
  uint4 u0 = sp[0], u1 = sp[1];
  int G0 = 2*hb, G1 = 2*hb + 1;
  unsigned short* dr = dstbuf + f*40;
  *(uint4*)(dr + (((G0 + f) & 3) << 3)) = u0;
  *(uint4*)(dr + (((G1 + f) & 3) << 3)) = u1;
}

// ---------------- cheb matmul (MFMA, 64 rows/wave), LDS-staged B, double-buffered ----------------
__global__ __launch_bounds__(256) void k_cheb(const unsigned short* __restrict__ T0,
                                              const unsigned short* __restrict__ T1,
                                              const unsigned short* __restrict__ T2,
                                              const unsigned short* __restrict__ Wct,
                                              const float* __restrict__ cb,
                                              unsigned short* __restrict__ outb){
  __shared__ unsigned short Bs[2][128*40];
  int t = threadIdx.x;
  int lane = t & 63, w = t >> 6;
  int c = lane & 15, g = lane >> 4;
  int rbase = blockIdx.x*256 + w*64;
  const unsigned short* Ts[3] = {T0, T1, T2};
  f32x4 acc[4][8];
  #pragma unroll
  for(int i=0;i<4;i++)
    #pragma unroll
    for(int j=0;j<8;j++) acc[i][j] = (f32x4){0.f,0.f,0.f,0.f};
  // slice s = kc*3+tm ; B slice base = Wct + tm*NH*NH + kc*32 (row stride NH)
  stageB(Wct + 0*NH*NH + 0*32, Bs[0], t);
  __syncthreads();
  for(int s=0; s<12; s++){
    int kc = s >> 2 == 0 ? s/3 : s/3;  // s/3
    kc = s/3; int tm = s - kc*3;
    if(s+1 < 12){
      int kc2 = (s+1)/3, tm2 = (s+1) - kc2*3;
      stageB(Wct + (size_t)tm2*NH*NH + kc2*32, Bs[(s+1)&1], t);
    }
    const unsigned short* Bb = Bs[s&1];
    short8 af[4];
    #pragma unroll
    for(int rt=0; rt<4; rt++){
      int m = rbase + rt*16 + c;
      int n = m >> 3, bl = m & 7;
      af[rt] = *(const short8*)(Ts[tm] + ((size_t)(bl*4+kc)*NN + n)*32 + 8*g);
    }
    #pragma unroll
    for(int ft=0; ft<8; ft++){
      int row = 16*ft + c;
      short8 bf_ = *(const short8*)(Bb + row*40 + (((g + row) & 3) << 3));
      #pragma unroll
      for(int rt=0; rt<4; rt++)
        acc[rt][ft] = __builtin_amdgcn_mfma_f32_16x16x32_bf16(af[rt], bf_, acc[rt][ft], 0, 0, 0);
    }
    __syncthreads();
  }
  float bias[8];
  #pragma unroll
  for(int ft=0; ft<8; ft++) bias[ft] = cb[16*ft + c];
  #pragma unroll
  for(int rt=0; rt<4; rt++){
    #pragma unroll
    for(int r=0;r<4;r++){
      int row = rbase + rt*16 + 4*g + r;
      int n = row >> 3, bl = row & 7;
      #pragma unroll
      for(int ft=0; ft<8; ft++){
        int f = 16*ft + c;
        outb[((size_t)(bl*4+(f>>5))*NN + n)*32 + (f&31)] = f2bf(acc[rt][ft][r] + bias[ft]);
      }
    }
  }
}

// ---------------- conv1d (MFMA, 64 rows/wave), LDS-staged B + bias + residual(f32) + LN + relu ----------------
// LAST=false: write h (f32, m-layout) + Hb (region layout).  LAST=true: fused output projection.
template<bool LAST>
__global__ __launch_bounds__(256) void k_conv(const unsigned short* __restrict__ Cin,
                                              const unsigned short* __restrict__ Wvt,
                                              const float* __restrict__ cb, const float* __restrict__ lg,
                                              const float* __restrict__ lb,
                                              float* __restrict__ H, unsigned short* __restrict__ Hb,
                                              const float* __restrict__ ow, const float* __restrict__ ob,
                                              float* __restrict__ out, int b0){
  __shared__ unsigned short Bs[2][128*40];
  int t = threadIdx.x;
  int lane = t & 63, w = t >> 6;
  int c = lane & 15, g = lane >> 4;
  int rbase = blockIdx.x*256 + w*64;
  f32x4 acc[4][8];
  #pragma unroll
  for(int i=0;i<4;i++)
    #pragma unroll
    for(int j=0;j<8;j++) acc[i][j] = (f32x4){0.f,0.f,0.f,0.f};
  short8 zf = {0,0,0,0,0,0,0,0};
  // slice s = ic*3+kw ; B slice base = Wvt + kw*NH*NH + ic*32 (row stride NH)
  stageB(Wvt + 0*NH*NH + 0*32, Bs[0], t);
  __syncthreads();
  for(int s=0; s<12; s++){
    int ic = s/3, kw = s - ic*3;
    if(s+1 < 12){
      int ic2 = (s+1)/3, kw2 = (s+1) - ic2*3;
      stageB(Wvt + (size_t)kw2*NH*NH + ic2*32, Bs[(s+1)&1], t);
    }
    const unsigned short* Bb = Bs[s&1];
    short8 af[4];
    #pragma unroll
    for(int rt=0; rt<4; rt++){
      int rowA = rbase + rt*16 + c + (kw-1)*BCK;   // node neighbor = m +/- BCK
      if((unsigned)rowA < (unsigned)NMC){
        int n = rowA >> 3, bl = rowA & 7;
        af[rt] = *(const short8*)(Cin + ((size_t)(bl*4+ic)*NN + n)*32 + 8*g);
      } else af[rt] = zf;
    }
    #pragma unroll
    for(int ft=0; ft<8; ft++){
      int row = 16*ft + c;
      short8 bf_ = *(const short8*)(Bb + row*40 + (((g + row) & 3) << 3));
      #pragma unroll
      for(int rt=0; rt<4; rt++)
        acc[rt][ft] = __builtin_amdgcn_mfma_f32_16x16x32_bf16(af[rt], bf_, acc[rt][ft], 0, 0, 0);
    }
    __syncthreads();
  }
  float cbv[8], gv[8], bv[8];
  #pragma unroll
  for(int ft=0; ft<8; ft++){
    int f = 16*ft + c;
    cbv[ft] = cb[f]; gv[ft] = lg[f]; bv[ft] = lb[f];
  }
  #pragma unroll
  for(int rt=0; rt<4; rt++){
    #pragma unroll
    for(int r=0;r<4;r++){
      int row = rbase + rt*16 + 4*g + r;
      size_t rbs = (size_t)row*NH;
      int n = row >> 3, bl = row & 7;
      float vals[8];
      float s = 0.f;
      #pragma unroll
      for(int ft=0; ft<8; ft++){
        float res = H[rbs + 16*ft + c];
        float v = acc[rt][ft][r] + cbv[ft] + res;
        vals[ft] = v;
        s += v;
      }
      s += __shfl_xor(s,1,64); s += __shfl_xor(s,2,64);
      s += __shfl_xor(s,4,64); s += __shfl_xor(s,8,64);
      float mu = s * (1.f/128.f);
      float q = 0.f;
      #pragma unroll
      for(int ft=0; ft<8; ft++){ float d = vals[ft]-mu; q += d*d; }
      q += __shfl_xor(q,1,64); q += __shfl_xor(q,2,64);
      q += __shfl_xor(q,4,64); q += __shfl_xor(q,8,64);
      float rs = rsqrtf(q*(1.f/128.f) + EPSV);
      if(!LAST){
        #pragma unroll
        for(int ft=0; ft<8; ft++){
          float y = (vals[ft]-mu)*rs*gv[ft] + bv[ft];
          y = fmaxf(y, 0.f);
          H[rbs + 16*ft + c] = y;
          int f = 16*ft + c;
          Hb[((size_t)(bl*4+(f>>5))*NN + n)*32 + (f&31)] = f2bf(y);
        }
      } else {
        float p0=0.f, p1=0.f, p2=0.f;
        #pragma unroll
        for(int ft=0; ft<8; ft++){
          float y = (vals[ft]-mu)*rs*gv[ft] + bv[ft];
          y = fmaxf(y, 0.f);
          int f = 16*ft + c;
          p0 = fmaf(y, ow[f*3+0], p0);
          p1 = fmaf(y, ow[f*3+1], p1);
          p2 = fmaf(y, ow[f*3+2], p2);
        }
        p0 += __shfl_xor(p0,1,64); p0 += __shfl_xor(p0,2,64);
        p0 += __shfl_xor(p0,4,64); p0 += __shfl_xor(p0,8,64);
        p1 += __shfl_xor(p1,1,64); p1 += __shfl_xor(p1,2,64);
        p1 += __shfl_xor(p1,4,64); p1 += __shfl_xor(p1,8,64);
        p2 += __shfl_xor(p2,1,64); p2 += __shfl_xor(p2,2,64);
        p2 += __shfl_xor(p2,4,64); p2 += __shfl_xor(p2,8,64);
        if(c==0){
          int nn = row >> 3, bl2 = b0 + (row & 7);
          out[((size_t)bl2*NP+0)*NN+nn] = p0 + ob[0];
          out[((size_t)bl2*NP+1)*NN+nn] = p1 + ob[1];
          out[((size_t)bl2*NP+2)*NN+nn] = p2 + ob[2];
        }
      }
    }
  }
}

extern "C" void kernel_launch(void* const* d_in, const int* in_sizes, int n_in,
                              void* d_out, int out_size, void* d_ws, size_t ws_size,
                              hipStream_t stream) {
  const float* x      = (const float*)d_in[0];
  const int*   ei     = (const int*)d_in[1];
  const float* in_w   = (const float*)d_in[2];
  const float* in_b   = (const float*)d_in[3];
  const float* cheb_w = (const float*)d_in[4];
  const float* cheb_b = (const float*)d_in[5];
  const float* conv_w = (const float*)d_in[6];
  const float* conv_b = (const float*)d_in[7];
  const float* ln_g   = (const float*)d_in[8];
  const float* ln_b   = (const float*)d_in[9];
  const float* out_w  = (const float*)d_in[10];
  const float* out_b  = (const float*)d_in[11];
  float* out = (float*)d_out;

  char* ws = (char*)d_ws;
  size_t off = 0;
  auto alloc = [&](size_t bytes)->void*{
    void* p = ws + off;
    off += (bytes + 255) & ~(size_t)255;
    return p;
  };
  // ---- fixed region (~6.3 MB) ----
  int* flag    = (int*)alloc(4);
  int* deg     = (int*)alloc(NN*4);
  int* cnt     = (int*)alloc(NN*4);
  int* fill    = (int*)alloc(NN*4);
  int* offs    = (int*)alloc((NN+1)*4);
  float* dis   = (float*)alloc(NN*4);
  int2* edata  = (int2*)alloc((size_t)NE*8);
  unsigned short* Wct = (unsigned short*)alloc((size_t)NL*3*NH*NH*2);
  unsigned short* Wvt = (unsigned short*)alloc((size_t)NL*3*NH*NH*2);
  // ---- chunk activation buffers: 82 + 3*41 MB = 205 MB ----
  const size_t fullb = ((size_t)NMC*NH*4 + 255) & ~(size_t)255;
  const size_t halfb = ((size_t)NMC*NH*2 + 255) & ~(size_t)255;
  float*          h   = (float*)alloc(fullb);
  unsigned short* hb  = (unsigned short*)alloc(halfb);
  unsigned short* t1b = (unsigned short*)alloc(halfb);
  unsigned short* t2b = (unsigned short*)alloc(halfb);

  hipMemsetAsync(deg, 0, NN*4, stream);
  hipMemsetAsync(cnt, 0, NN*4, stream);
  hipMemsetAsync(fill, 0, NN*4, stream);

  k_detect<<<1,256,0,stream>>>(ei,flag);
  k_count<<<(NE+255)/256,256,0,stream>>>(ei,flag,deg,cnt);
  k_dis<<<(NN+255)/256,256,0,stream>>>(deg,dis);
  k_scan<<<1,1024,0,stream>>>(cnt,offs);
  k_scatter<<<(NE+255)/256,256,0,stream>>>(ei,flag,offs,fill,dis,edata);
  k_sortseg<<<NN,64,0,stream>>>(offs,edata);
  k_prepw<<<(NL*3*NH*NH+255)/256,256,0,stream>>>(cheb_w,conv_w,Wct,Wvt);

  for(int b0=0; b0<NB; b0+=BCK){
    k_inproj<<<NMC/4,256,0,stream>>>(x,in_w,in_b,h,(unsigned int*)hb,b0);
    for(int l=0;l<NL;l++){
      k_prop<false><<<NREG*NGPB,256,0,stream>>>((const uint4*)hb,  nullptr,
                                                (uint4*)t1b, offs, edata);
      k_prop<true ><<<NREG*NGPB,256,0,stream>>>((const uint4*)t1b, (const uint4*)hb,
                                                (uint4*)t2b, offs, edata);
      k_cheb<<<NGEMM,256,0,stream>>>(hb, t1b, t2b, Wct + (size_t)l*3*NH*NH,
                                     cheb_b + l*NH, t2b);
      if(l==0)
        k_conv<false><<<NGEMM,256,0,stream>>>(t2b, Wvt + (size_t)l*3*NH*NH, conv_b + l*NH,
                                              ln_g + l*NH, ln_b + l*NH, h, hb,
                                              out_w, out_b, out, b0);
      else
        k_conv<true ><<<NGEMM,256,0,stream>>>(t2b, Wvt + (size_t)l*3*NH*NH, conv_b + l*NH,
                                              ln_g + l*NH, ln_b + l*NH, h, hb,
                                              out_w, out_b, out, b0);
    }
  }
}